// Round 2
// baseline (1395.255 us; speedup 1.0000x reference)
//
#include <hip/hip_runtime.h>
#include <hip/hip_bf16.h>
#include <cmath>

// Problem constants (fixed shapes)
#define NN 2048
#define DIN 768
#define DHID 1024
#define NHEADS 8
#define FPRIME 128
#define DFFN 2048
#define SEN_LIM 2042   // sen branch: columns j < 2042; sec branch: j >= 2042

// ---------------------------------------------------------------------------
// Neighbor-list construction: for each row i, compact indices j where adj!=0,
// split into sen (j < 2042) and sec (j >= 2042) lists. Order irrelevant
// (softmax + weighted sum are order-independent up to fp rounding).
// ---------------------------------------------------------------------------
__global__ __launch_bounds__(256) void build_nbrs(
    const float* __restrict__ adj,
    unsigned short* __restrict__ sen_idx, int* __restrict__ sen_cnt,
    unsigned short* __restrict__ sec_idx, int* __restrict__ sec_cnt)
{
    const int i = blockIdx.x;
    __shared__ int c_sen, c_sec;
    if (threadIdx.x == 0) { c_sen = 0; c_sec = 0; }
    __syncthreads();
    for (int j = threadIdx.x; j < NN; j += 256) {
        float v = adj[(size_t)i * NN + j];
        if (v != 0.0f) {
            if (j < SEN_LIM) {
                int p = atomicAdd(&c_sen, 1);
                sen_idx[(size_t)i * NN + p] = (unsigned short)j;
            } else {
                int p = atomicAdd(&c_sec, 1);
                sec_idx[i * 8 + p] = (unsigned short)j;
            }
        }
    }
    __syncthreads();
    if (threadIdx.x == 0) { sen_cnt[i] = c_sen; sec_cnt[i] = c_sec; }
}

// ---------------------------------------------------------------------------
// Generic f32 GEMM: C[M,N] = act(A[M,K] @ B[K,N] + bias) (+ resid)
// 64x64 tile, 256 threads, 4x4 microtile, K-step 16. All dims %64 / %16 == 0.
// act: 0 = none, 1 = leaky(0.01)
// ---------------------------------------------------------------------------
__global__ __launch_bounds__(256) void gemm_f32(
    const float* __restrict__ A, const float* __restrict__ B,
    const float* __restrict__ bias, const float* __restrict__ resid,
    float* __restrict__ C, int M, int N, int K, int act)
{
    __shared__ __align__(16) float As[16][68];  // [k][m], row = 272B -> 16B aligned
    __shared__ __align__(16) float Bs[16][68];  // [k][n]
    const int tid = threadIdx.x;
    const int tx = tid & 15, ty = tid >> 4;
    const int bm = blockIdx.y * 64, bn = blockIdx.x * 64;

    float acc[4][4] = {};

    for (int k0 = 0; k0 < K; k0 += 16) {
        #pragma unroll
        for (int l = 0; l < 4; ++l) {
            int idx = tid + l * 256;
            int r = idx >> 4, c = idx & 15;       // A tile: 64 rows x 16 k
            As[c][r] = A[(size_t)(bm + r) * K + (k0 + c)];
            int rb = idx >> 6, cb = idx & 63;     // B tile: 16 k x 64 cols
            Bs[rb][cb] = B[(size_t)(k0 + rb) * N + (bn + cb)];
        }
        __syncthreads();
        #pragma unroll
        for (int kk = 0; kk < 16; ++kk) {
            float4 av = *(const float4*)&As[kk][ty * 4];
            float4 bv = *(const float4*)&Bs[kk][tx * 4];
            acc[0][0] += av.x * bv.x; acc[0][1] += av.x * bv.y;
            acc[0][2] += av.x * bv.z; acc[0][3] += av.x * bv.w;
            acc[1][0] += av.y * bv.x; acc[1][1] += av.y * bv.y;
            acc[1][2] += av.y * bv.z; acc[1][3] += av.y * bv.w;
            acc[2][0] += av.z * bv.x; acc[2][1] += av.z * bv.y;
            acc[2][2] += av.z * bv.z; acc[2][3] += av.z * bv.w;
            acc[3][0] += av.w * bv.x; acc[3][1] += av.w * bv.y;
            acc[3][2] += av.w * bv.z; acc[3][3] += av.w * bv.w;
        }
        __syncthreads();
    }

    #pragma unroll
    for (int ii = 0; ii < 4; ++ii) {
        int row = bm + ty * 4 + ii;
        #pragma unroll
        for (int jj = 0; jj < 4; ++jj) {
            int col = bn + tx * 4 + jj;
            float v = acc[ii][jj];
            if (bias)  v += bias[col];
            if (act)   v = (v >= 0.f) ? v : 0.01f * v;
            if (resid) v += resid[(size_t)row * N + col];
            C[(size_t)row * N + col] = v;
        }
    }
}

// ---------------------------------------------------------------------------
// gl[b] = sum_f g[b*F+f]*a[f]; gr[b] = sum_f g[b*F+f]*a[F+f]
// One wave per (node,head) row of g viewed as [NN*H, F].
// ---------------------------------------------------------------------------
__global__ __launch_bounds__(64) void glgr_kernel(
    const float* __restrict__ g, const float* __restrict__ a,
    int F, float* __restrict__ gl, float* __restrict__ gr)
{
    const int b = blockIdx.x;
    const int lane = threadIdx.x;
    const float* gb = g + (size_t)b * F;
    float sl = 0.f, sr = 0.f;
    for (int f = lane; f < F; f += 64) {
        float v = gb[f];
        sl += v * a[f];
        sr += v * a[F + f];
    }
    #pragma unroll
    for (int off = 32; off > 0; off >>= 1) {
        sl += __shfl_down(sl, off);
        sr += __shfl_down(sr, off);
    }
    if (lane == 0) { gl[b] = sl; gr[b] = sr; }
}

__global__ __launch_bounds__(256) void zero_f32(float* p, int n)
{
    int t = blockIdx.x * 256 + threadIdx.x;
    if (t < n) p[t] = 0.f;
}

// out[c] += (1/2048) * sum over a 128-row slab of g[r*C+c]  (out pre-zeroed)
__global__ __launch_bounds__(256) void col_mean(
    const float* __restrict__ g, int C, float* __restrict__ out)
{
    int c = blockIdx.x * 256 + threadIdx.x;
    int r0 = blockIdx.y * 128;
    float s = 0.f;
    for (int r = r0; r < r0 + 128; ++r) s += g[(size_t)r * C + c];
    atomicAdd(&out[c], s * (1.0f / 2048.0f));
}

// ---------------------------------------------------------------------------
// Sparse GAT attention + aggregation, one block per destination node i.
//   scores: s_ijh = leaky0.2(gl[i,h] + gr[j,h]) over neighbor list
//   out[i,h,:] = sum_j softmax_j(s) * g[j,h,:]
// n==0 rows: softmax over all-(-1e9) is uniform -> out = column mean of g.
// mode 0: elu epilogue (layer-1). mode 1: += resid (layer-2, residual +x).
// ---------------------------------------------------------------------------
template<int H, int F>
__global__ __launch_bounds__(256) void attn_agg(
    const float* __restrict__ g,            // [NN, H*F]
    const float* __restrict__ gl,           // [NN, H]
    const float* __restrict__ gr,           // [NN, H]
    const unsigned short* __restrict__ idx, // [NN, idx_stride]
    int idx_stride,
    const int* __restrict__ cnt,            // [NN]
    const float* __restrict__ gmean,        // [H*F]  column mean of g
    float* __restrict__ dst,
    int dst_stride, int dst_coloff,
    const float* __restrict__ resid,        // [NN, H*F] or null
    int mode)
{
    constexpr int HF = H * F;
    constexpr int NACC = HF / 256;
    const int i = blockIdx.x;
    const int tid = threadIdx.x;
    const int n = cnt[i];

    if (n == 0) {
        for (int c = tid; c < HF; c += 256) {
            float v = gmean[c];
            if (mode == 0) v = (v > 0.f) ? v : expm1f(v);
            else           v += resid[(size_t)i * HF + c];
            dst[(size_t)i * dst_stride + dst_coloff + c] = v;
        }
        return;
    }

    __shared__ float s_red[256];
    __shared__ float s_max[H], s_inv[H], s_glh[H];
    __shared__ float s_w[128 * H];
    __shared__ unsigned short s_j[128];

    if (tid < H) s_glh[tid] = gl[(size_t)i * H + tid];
    __syncthreads();

    const unsigned short* row_idx = idx + (size_t)i * idx_stride;

    // Pass 1: per-head max over neighbors
    float pmax[H];
    #pragma unroll
    for (int h = 0; h < H; ++h) pmax[h] = -1e30f;
    for (int jj = tid; jj < n; jj += 256) {
        int j = row_idx[jj];
        #pragma unroll
        for (int h = 0; h < H; ++h) {
            float s = s_glh[h] + gr[j * H + h];
            s = (s >= 0.f) ? s : 0.2f * s;
            pmax[h] = fmaxf(pmax[h], s);
        }
    }
    #pragma unroll
    for (int h = 0; h < H; ++h) {
        __syncthreads();
        s_red[tid] = pmax[h];
        __syncthreads();
        for (int st = 128; st > 0; st >>= 1) {
            if (tid < st) s_red[tid] = fmaxf(s_red[tid], s_red[tid + st]);
            __syncthreads();
        }
        if (tid == 0) s_max[h] = s_red[0];
    }
    __syncthreads();

    // Pass 2: per-head sum of exp
    float psum[H];
    #pragma unroll
    for (int h = 0; h < H; ++h) psum[h] = 0.f;
    for (int jj = tid; jj < n; jj += 256) {
        int j = row_idx[jj];
        #pragma unroll
        for (int h = 0; h < H; ++h) {
            float s = s_glh[h] + gr[j * H + h];
            s = (s >= 0.f) ? s : 0.2f * s;
            psum[h] += expf(s - s_max[h]);
        }
    }
    #pragma unroll
    for (int h = 0; h < H; ++h) {
        __syncthreads();
        s_red[tid] = psum[h];
        __syncthreads();
        for (int st = 128; st > 0; st >>= 1) {
            if (tid < st) s_red[tid] += s_red[tid + st];
            __syncthreads();
        }
        if (tid == 0) s_inv[h] = 1.f / s_red[0];
    }
    __syncthreads();

    // Pass 3: chunked weighted aggregation. acc[k] covers column tid + 256k.
    float acc[NACC];
    #pragma unroll
    for (int k = 0; k < NACC; ++k) acc[k] = 0.f;

    for (int c0 = 0; c0 < n; c0 += 128) {
        int m = min(128, n - c0);
        __syncthreads();  // protect s_w/s_j reuse
        for (int e = tid; e < m * H; e += 256) {
            int jj = (H == 8) ? (e >> 3) : e;
            int h  = (H == 8) ? (e & 7) : 0;
            int j = row_idx[c0 + jj];
            float s = s_glh[h] + gr[j * H + h];
            s = (s >= 0.f) ? s : 0.2f * s;
            s_w[jj * H + h] = expf(s - s_max[h]) * s_inv[h];
            if (h == 0) s_j[jj] = (unsigned short)j;
        }
        __syncthreads();
        for (int jj = 0; jj < m; ++jj) {
            const float* gj = g + (size_t)s_j[jj] * HF;
            #pragma unroll
            for (int k = 0; k < NACC; ++k) {
                int c = tid + k * 256;
                int h = (F == 128) ? (c >> 7) : 0;
                acc[k] += s_w[jj * H + h] * gj[c];
            }
        }
    }

    #pragma unroll
    for (int k = 0; k < NACC; ++k) {
        int c = tid + k * 256;
        float v = acc[k];
        if (mode == 0) v = (v > 0.f) ? v : expm1f(v);
        else           v += resid[(size_t)i * HF + c];
        dst[(size_t)i * dst_stride + dst_coloff + c] = v;
    }
}

// ---------------------------------------------------------------------------
extern "C" void kernel_launch(void* const* d_in, const int* in_sizes, int n_in,
                              void* d_out, int out_size, void* d_ws, size_t ws_size,
                              hipStream_t stream)
{
    const float* feature = (const float*)d_in[0];
    const float* adj     = (const float*)d_in[1];
    const float* g1W1 = (const float*)d_in[2];
    const float* g1a1 = (const float*)d_in[3];
    const float* g1W2 = (const float*)d_in[4];
    const float* g1a2 = (const float*)d_in[5];
    const float* g2W1 = (const float*)d_in[6];
    const float* g2a1 = (const float*)d_in[7];
    const float* g2W2 = (const float*)d_in[8];
    const float* g2a2 = (const float*)d_in[9];
    const float* Wf  = (const float*)d_in[10];
    const float* bfv = (const float*)d_in[11];
    const float* fW1 = (const float*)d_in[12];
    const float* fb1 = (const float*)d_in[13];
    const float* fW2 = (const float*)d_in[14];
    const float* fb2 = (const float*)d_in[15];
    const float* fW3 = (const float*)d_in[16];
    const float* fb3 = (const float*)d_in[17];
    const float* oW1 = (const float*)d_in[18];
    const float* ob1 = (const float*)d_in[19];
    const float* oW2 = (const float*)d_in[20];
    const float* ob2 = (const float*)d_in[21];
    float* out = (float*)d_out;

    // workspace layout (~80 MB)
    char* ws = (char*)d_ws;
    size_t off = 0;
    auto alloc = [&](size_t bytes) -> void* {
        void* p = ws + off;
        off = (off + bytes + 255) & ~(size_t)255;
        return p;
    };
    int* sen_cnt = (int*)alloc((size_t)NN * 4);
    int* sec_cnt = (int*)alloc((size_t)NN * 4);
    unsigned short* sen_idx = (unsigned short*)alloc((size_t)NN * NN * 2);
    unsigned short* sec_idx = (unsigned short*)alloc((size_t)NN * 8 * 2);
    float* g1buf = (float*)alloc((size_t)NN * DHID * 4);
    float* gl1   = (float*)alloc((size_t)NN * NHEADS * 4);
    float* gr1   = (float*)alloc((size_t)NN * NHEADS * 4);
    float* x1    = (float*)alloc((size_t)NN * DHID * 4);
    float* g2buf = (float*)alloc((size_t)NN * DIN * 4);
    float* gl2   = (float*)alloc((size_t)NN * 4);
    float* gr2   = (float*)alloc((size_t)NN * 4);
    float* gmean = (float*)alloc((size_t)DHID * 4);
    float* fcat  = (float*)alloc((size_t)NN * (2 * DIN) * 4);
    float* fbuf  = (float*)alloc((size_t)NN * DIN * 4);
    float* tA    = (float*)alloc((size_t)NN * DFFN * 4);
    float* tB    = (float*)alloc((size_t)NN * DFFN * 4);

    build_nbrs<<<NN, 256, 0, stream>>>(adj, sen_idx, sen_cnt, sec_idx, sec_cnt);

    auto run_gat = [&](const float* W1, const float* a1, const float* W2, const float* a2,
                       const unsigned short* idx, int idx_stride, const int* cnt, int coloff) {
        // layer 1: g1 = x @ W1  [2048,1024]
        gemm_f32<<<dim3(DHID / 64, NN / 64), 256, 0, stream>>>(
            feature, W1, nullptr, nullptr, g1buf, NN, DHID, DIN, 0);
        glgr_kernel<<<NN * NHEADS, 64, 0, stream>>>(g1buf, a1, FPRIME, gl1, gr1);
        zero_f32<<<DHID / 256, 256, 0, stream>>>(gmean, DHID);
        col_mean<<<dim3(DHID / 256, 16), 256, 0, stream>>>(g1buf, DHID, gmean);
        attn_agg<NHEADS, FPRIME><<<NN, 256, 0, stream>>>(
            g1buf, gl1, gr1, idx, idx_stride, cnt, gmean, x1, DHID, 0, nullptr, 0);
        // layer 2: g2 = x1 @ W2  [2048,768]
        gemm_f32<<<dim3(DIN / 64, NN / 64), 256, 0, stream>>>(
            x1, W2, nullptr, nullptr, g2buf, NN, DIN, DHID, 0);
        glgr_kernel<<<NN, 64, 0, stream>>>(g2buf, a2, DIN, gl2, gr2);
        zero_f32<<<DIN / 256, 256, 0, stream>>>(gmean, DIN);
        col_mean<<<dim3(DIN / 256, 16), 256, 0, stream>>>(g2buf, DIN, gmean);
        // write f_branch + x into fcat columns [coloff, coloff+768)
        attn_agg<1, DIN><<<NN, 256, 0, stream>>>(
            g2buf, gl2, gr2, idx, idx_stride, cnt, gmean, fcat, 2 * DIN, coloff, feature, 1);
    };

    // f_sen = gat(gat1_*, sen lists) + x  -> fcat[:, 768:1536]
    run_gat(g1W1, g1a1, g1W2, g1a2, sen_idx, NN, sen_cnt, DIN);
    // f_sec = gat(gat2_*, sec lists) + x  -> fcat[:, 0:768]
    run_gat(g2W1, g2a1, g2W2, g2a2, sec_idx, 8, sec_cnt, 0);

    // fusion: fbuf = leaky(fcat @ Wf + bf)
    gemm_f32<<<dim3(DIN / 64, NN / 64), 256, 0, stream>>>(
        fcat, Wf, bfv, nullptr, fbuf, NN, DIN, 2 * DIN, 1);
    // ffn (3 layers, leaky on all)
    gemm_f32<<<dim3(DFFN / 64, NN / 64), 256, 0, stream>>>(
        fbuf, fW1, fb1, nullptr, tA, NN, DFFN, DIN, 1);
    gemm_f32<<<dim3(DFFN / 64, NN / 64), 256, 0, stream>>>(
        tA, fW2, fb2, nullptr, tB, NN, DFFN, DFFN, 1);
    gemm_f32<<<dim3(DIN / 64, NN / 64), 256, 0, stream>>>(
        tB, fW3, fb3, nullptr, fbuf, NN, DIN, DFFN, 1);
    // out mlp (2 layers, leaky on both), final residual +x fused into last GEMM
    gemm_f32<<<dim3(DFFN / 64, NN / 64), 256, 0, stream>>>(
        fbuf, oW1, ob1, nullptr, tA, NN, DFFN, DIN, 1);
    gemm_f32<<<dim3(DIN / 64, NN / 64), 256, 0, stream>>>(
        tA, oW2, ob2, feature, out, NN, DIN, DFFN, 1);
}

// Round 3
// 655.876 us; speedup vs baseline: 2.1273x; 2.1273x over previous
//
#include <hip/hip_runtime.h>
#include <hip/hip_bf16.h>
#include <cmath>

#define NN 2048
#define DIN 768
#define DHID 1024
#define NHEADS 8
#define FPRIME 128
#define DFFN 2048
#define SEN_LIM 2042
#define MAXDEG 256

using short8 = __attribute__((ext_vector_type(8))) short;
using f32x4  = __attribute__((ext_vector_type(4))) float;

__device__ inline unsigned short f2bf(float f) {
    unsigned u = __float_as_uint(f);
    unsigned r = u + 0x7FFFu + ((u >> 16) & 1u);   // RNE
    return (unsigned short)(r >> 16);
}
__device__ inline float bf2f(unsigned short h) {
    return __uint_as_float(((unsigned)h) << 16);
}
__device__ inline void store_out(float* p, float v) { *p = v; }
__device__ inline void store_out(unsigned short* p, float v) { *p = f2bf(v); }

// ---------------------------------------------------------------------------
// Neighbor lists (sen: j<2042, capped 256; sec: j>=2042, capped 8)
// ---------------------------------------------------------------------------
__global__ __launch_bounds__(256) void build_nbrs(
    const float* __restrict__ adj,
    unsigned short* __restrict__ sen_idx, int* __restrict__ sen_cnt,
    unsigned short* __restrict__ sec_idx, int* __restrict__ sec_cnt)
{
    const int i = blockIdx.x;
    __shared__ int c_sen, c_sec;
    if (threadIdx.x == 0) { c_sen = 0; c_sec = 0; }
    __syncthreads();
    for (int j = threadIdx.x; j < NN; j += 256) {
        float v = adj[(size_t)i * NN + j];
        if (v != 0.0f) {
            if (j < SEN_LIM) {
                int p = atomicAdd(&c_sen, 1);
                if (p < MAXDEG) sen_idx[(size_t)i * MAXDEG + p] = (unsigned short)j;
            } else {
                int p = atomicAdd(&c_sec, 1);
                if (p < 8) sec_idx[i * 8 + p] = (unsigned short)j;
            }
        }
    }
    __syncthreads();
    if (threadIdx.x == 0) { sen_cnt[i] = min(c_sen, MAXDEG); sec_cnt[i] = min(c_sec, 8); }
}

// ---------------------------------------------------------------------------
// Transpose + cast: W[K][N] f32 -> WT[N][K] bf16
// ---------------------------------------------------------------------------
__global__ __launch_bounds__(256) void transpose_cast(
    const float* __restrict__ W, unsigned short* __restrict__ WT, int K, int N)
{
    __shared__ float t[32][33];
    const int bn = blockIdx.x * 32, bk = blockIdx.y * 32;
    const int tx = threadIdx.x & 31, ty = threadIdx.x >> 5;
    #pragma unroll
    for (int r = 0; r < 4; ++r)
        t[ty + r * 8][tx] = W[(size_t)(bk + ty + r * 8) * N + bn + tx];
    __syncthreads();
    #pragma unroll
    for (int r = 0; r < 4; ++r) {
        int n = ty + r * 8;
        WT[(size_t)(bn + n) * K + bk + tx] = f2bf(t[tx][n]);
    }
}

__global__ __launch_bounds__(256) void cast_bf16(
    const float* __restrict__ in, unsigned short* __restrict__ out, int n)
{
    int t = blockIdx.x * 256 + threadIdx.x;
    if (t < n) out[t] = f2bf(in[t]);
}

__global__ __launch_bounds__(256) void zero_f32(float* p, int n)
{
    int t = blockIdx.x * 256 + threadIdx.x;
    if (t < n) p[t] = 0.f;
}

__global__ __launch_bounds__(256) void col_mean(
    const float* __restrict__ g, int C, float* __restrict__ out)
{
    int c = blockIdx.x * 256 + threadIdx.x;
    int r0 = blockIdx.y * 128;
    float s = 0.f;
    for (int r = r0; r < r0 + 128; ++r) s += g[(size_t)r * C + c];
    atomicAdd(&out[c], s * (1.0f / 2048.0f));
}

// ---------------------------------------------------------------------------
// bf16 MFMA GEMM: C[M,N] = act(A[M,K]@B[K,N] + bias) (+resid)
// A bf16 row-major, BT = B^T bf16 [N][K]. BM=128, BK=64, BN template (128/64).
// 256 threads = 4 waves in 2x2; per-wave 64 x BN/2; 16x16x32 MFMA frags.
// ---------------------------------------------------------------------------
template<int BN, typename OUT_T>
__global__ __launch_bounds__(256) void gemm_mfma(
    const unsigned short* __restrict__ A, const unsigned short* __restrict__ BT,
    const float* __restrict__ bias, const float* __restrict__ resid,
    OUT_T* __restrict__ C, int M, int N, int K, int act)
{
    constexpr int BM = 128, BK = 64;
    constexpr int NF = BN / 32;              // N-frags per wave (4 or 2)
    __shared__ unsigned short Asm[BM * BK];
    __shared__ unsigned short Bsm[BN * BK];
    const int tid = threadIdx.x;
    const int lane = tid & 63, w = tid >> 6;
    const int wr = w >> 1, wc = w & 1;
    const int bm = blockIdx.y * BM, bn = blockIdx.x * BN;

    f32x4 acc[4][NF];
    #pragma unroll
    for (int mi = 0; mi < 4; ++mi)
        #pragma unroll
        for (int ni = 0; ni < NF; ++ni)
            acc[mi][ni] = (f32x4){0.f, 0.f, 0.f, 0.f};

    const unsigned short* Abase = A + (size_t)bm * K;
    const unsigned short* Bbase = BT + (size_t)bn * K;

    for (int k0 = 0; k0 < K; k0 += BK) {
        __syncthreads();
        #pragma unroll
        for (int c = 0; c < 4; ++c) {               // A: 128x64 = 8192 elems
            int e = tid * 8 + c * 2048;
            int r = e >> 6, kk = e & 63;
            *(short8*)&Asm[e] = *(const short8*)&Abase[(size_t)r * K + k0 + kk];
        }
        #pragma unroll
        for (int c = 0; c < NF; ++c) {              // B: BN x 64
            int e = tid * 8 + c * 2048;
            int r = e >> 6, kk = e & 63;
            *(short8*)&Bsm[e] = *(const short8*)&Bbase[(size_t)r * K + k0 + kk];
        }
        __syncthreads();
        #pragma unroll
        for (int ks = 0; ks < 2; ++ks) {
            short8 af[4], bfv[NF];
            #pragma unroll
            for (int mi = 0; mi < 4; ++mi)
                af[mi] = *(const short8*)&Asm[(wr * 64 + mi * 16 + (lane & 15)) * 64
                                              + ks * 32 + (lane >> 4) * 8];
            #pragma unroll
            for (int ni = 0; ni < NF; ++ni)
                bfv[ni] = *(const short8*)&Bsm[(wc * (BN / 2) + ni * 16 + (lane & 15)) * 64
                                               + ks * 32 + (lane >> 4) * 8];
            #pragma unroll
            for (int mi = 0; mi < 4; ++mi)
                #pragma unroll
                for (int ni = 0; ni < NF; ++ni)
                    acc[mi][ni] = __builtin_amdgcn_mfma_f32_16x16x32_bf16(
                        af[mi], bfv[ni], acc[mi][ni], 0, 0, 0);
        }
    }

    const int rbase = bm + wr * 64;
    const int cbase = bn + wc * (BN / 2);
    #pragma unroll
    for (int mi = 0; mi < 4; ++mi)
        #pragma unroll
        for (int ni = 0; ni < NF; ++ni)
            #pragma unroll
            for (int r = 0; r < 4; ++r) {
                int grow = rbase + mi * 16 + (lane >> 4) * 4 + r;
                int gcol = cbase + ni * 16 + (lane & 15);
                float v = acc[mi][ni][r];
                if (bias)  v += bias[gcol];
                if (act)   v = (v >= 0.f) ? v : 0.01f * v;
                if (resid) v += resid[(size_t)grow * N + gcol];
                store_out(&C[(size_t)grow * N + gcol], v);
            }
}

// ---------------------------------------------------------------------------
// gl/gr dot products (g f32)
// ---------------------------------------------------------------------------
__global__ __launch_bounds__(64) void glgr_kernel(
    const float* __restrict__ g, const float* __restrict__ a,
    int F, float* __restrict__ gl, float* __restrict__ gr)
{
    const int b = blockIdx.x;
    const int lane = threadIdx.x;
    const float* gb = g + (size_t)b * F;
    float sl = 0.f, sr = 0.f;
    for (int f = lane; f < F; f += 64) {
        float v = gb[f];
        sl += v * a[f];
        sr += v * a[F + f];
    }
    #pragma unroll
    for (int off = 32; off > 0; off >>= 1) {
        sl += __shfl_down(sl, off);
        sr += __shfl_down(sr, off);
    }
    if (lane == 0) { gl[b] = sl; gr[b] = sr; }
}

// ---------------------------------------------------------------------------
// Sparse GAT attention+aggregation. Wave-shuffle reductions (4 barriers total
// in passes 1-2 instead of ~160 block-tree barriers). Pass-3 unrolled x4.
// mode 0: ELU epilogue; mode 1: += resid. OUT_T: bf16 (ushort) or float.
// ---------------------------------------------------------------------------
template<int H, int F, typename OUT_T>
__global__ __launch_bounds__(256) void attn_agg(
    const float* __restrict__ g,
    const float* __restrict__ gl,
    const float* __restrict__ gr,
    const unsigned short* __restrict__ idx, int idx_stride,
    const int* __restrict__ cnt,
    const float* __restrict__ gmean,
    OUT_T* __restrict__ dst, int dst_stride, int dst_coloff,
    const float* __restrict__ resid, int mode)
{
    constexpr int HF = H * F;
    constexpr int NACC = HF / 256;
    const int i = blockIdx.x;
    const int tid = threadIdx.x;
    const int lane = tid & 63, w = tid >> 6;
    const int n = cnt[i];

    if (n == 0) {
        for (int c = tid; c < HF; c += 256) {
            float v = gmean[c];
            if (mode == 0) v = (v > 0.f) ? v : expm1f(v);
            else           v += resid[(size_t)i * HF + c];
            store_out(&dst[(size_t)i * dst_stride + dst_coloff + c], v);
        }
        return;
    }

    __shared__ float s_wred[4 * H];
    __shared__ float s_max[H], s_inv[H], s_glh[H];
    __shared__ float s_w[128 * H];
    __shared__ unsigned short s_j[128];

    if (tid < H) s_glh[tid] = gl[(size_t)i * H + tid];
    __syncthreads();
    float glh[H];
    #pragma unroll
    for (int h = 0; h < H; ++h) glh[h] = s_glh[h];

    const unsigned short* row_idx = idx + (size_t)i * idx_stride;

    // Pass 1: per-head max (wave shuffle + cross-wave LDS)
    float pmax[H];
    #pragma unroll
    for (int h = 0; h < H; ++h) pmax[h] = -1e30f;
    for (int jj = tid; jj < n; jj += 256) {
        int j = row_idx[jj];
        #pragma unroll
        for (int h = 0; h < H; ++h) {
            float s = glh[h] + gr[j * H + h];
            s = (s >= 0.f) ? s : 0.2f * s;
            pmax[h] = fmaxf(pmax[h], s);
        }
    }
    #pragma unroll
    for (int h = 0; h < H; ++h)
        #pragma unroll
        for (int off = 32; off > 0; off >>= 1)
            pmax[h] = fmaxf(pmax[h], __shfl_xor(pmax[h], off));
    if (lane == 0)
        #pragma unroll
        for (int h = 0; h < H; ++h) s_wred[w * H + h] = pmax[h];
    __syncthreads();
    if (tid < H)
        s_max[tid] = fmaxf(fmaxf(s_wred[tid], s_wred[H + tid]),
                           fmaxf(s_wred[2 * H + tid], s_wred[3 * H + tid]));
    __syncthreads();
    float mx[H];
    #pragma unroll
    for (int h = 0; h < H; ++h) mx[h] = s_max[h];

    // Pass 2: per-head exp-sum
    float psum[H];
    #pragma unroll
    for (int h = 0; h < H; ++h) psum[h] = 0.f;
    for (int jj = tid; jj < n; jj += 256) {
        int j = row_idx[jj];
        #pragma unroll
        for (int h = 0; h < H; ++h) {
            float s = glh[h] + gr[j * H + h];
            s = (s >= 0.f) ? s : 0.2f * s;
            psum[h] += expf(s - mx[h]);
        }
    }
    #pragma unroll
    for (int h = 0; h < H; ++h)
        #pragma unroll
        for (int off = 32; off > 0; off >>= 1)
            psum[h] += __shfl_xor(psum[h], off);
    if (lane == 0)
        #pragma unroll
        for (int h = 0; h < H; ++h) s_wred[w * H + h] = psum[h];
    __syncthreads();
    if (tid < H)
        s_inv[tid] = 1.f / (s_wred[tid] + s_wred[H + tid] +
                            s_wred[2 * H + tid] + s_wred[3 * H + tid]);
    // barrier provided by first iteration of pass-3 loop

    // Pass 3: chunked weighted aggregation, unrolled x4
    float acc[NACC];
    #pragma unroll
    for (int k = 0; k < NACC; ++k) acc[k] = 0.f;

    for (int c0 = 0; c0 < n; c0 += 128) {
        int m = min(128, n - c0);
        __syncthreads();
        for (int e = tid; e < m * H; e += 256) {
            int jj = (H == 8) ? (e >> 3) : e;
            int h  = (H == 8) ? (e & 7) : 0;
            int j = row_idx[c0 + jj];
            float s = glh[h] + gr[j * H + h];
            s = (s >= 0.f) ? s : 0.2f * s;
            s_w[jj * H + h] = expf(s - s_max[h]) * s_inv[h];
            if (h == 0) s_j[jj] = (unsigned short)j;
        }
        __syncthreads();
        int jj = 0;
        for (; jj + 4 <= m; jj += 4) {
            const float* g0 = g + (size_t)s_j[jj] * HF;
            const float* g1 = g + (size_t)s_j[jj + 1] * HF;
            const float* g2 = g + (size_t)s_j[jj + 2] * HF;
            const float* g3 = g + (size_t)s_j[jj + 3] * HF;
            #pragma unroll
            for (int k = 0; k < NACC; ++k) {
                int c = tid + k * 256;
                int h = (F == 128) ? (c >> 7) : 0;
                acc[k] += s_w[jj * H + h] * g0[c];
                acc[k] += s_w[(jj + 1) * H + h] * g1[c];
                acc[k] += s_w[(jj + 2) * H + h] * g2[c];
                acc[k] += s_w[(jj + 3) * H + h] * g3[c];
            }
        }
        for (; jj < m; ++jj) {
            const float* gj = g + (size_t)s_j[jj] * HF;
            #pragma unroll
            for (int k = 0; k < NACC; ++k) {
                int c = tid + k * 256;
                int h = (F == 128) ? (c >> 7) : 0;
                acc[k] += s_w[jj * H + h] * gj[c];
            }
        }
    }

    #pragma unroll
    for (int k = 0; k < NACC; ++k) {
        int c = tid + k * 256;
        float v = acc[k];
        if (mode == 0) v = (v > 0.f) ? v : expm1f(v);
        else           v += resid[(size_t)i * HF + c];
        store_out(&dst[(size_t)i * dst_stride + dst_coloff + c], v);
    }
}

// ---------------------------------------------------------------------------
extern "C" void kernel_launch(void* const* d_in, const int* in_sizes, int n_in,
                              void* d_out, int out_size, void* d_ws, size_t ws_size,
                              hipStream_t stream)
{
    const float* feature = (const float*)d_in[0];
    const float* adj     = (const float*)d_in[1];
    const float* g1W1 = (const float*)d_in[2];
    const float* g1a1 = (const float*)d_in[3];
    const float* g1W2 = (const float*)d_in[4];
    const float* g1a2 = (const float*)d_in[5];
    const float* g2W1 = (const float*)d_in[6];
    const float* g2a1 = (const float*)d_in[7];
    const float* g2W2 = (const float*)d_in[8];
    const float* g2a2 = (const float*)d_in[9];
    const float* Wf  = (const float*)d_in[10];
    const float* bfv = (const float*)d_in[11];
    const float* fW1 = (const float*)d_in[12];
    const float* fb1 = (const float*)d_in[13];
    const float* fW2 = (const float*)d_in[14];
    const float* fb2 = (const float*)d_in[15];
    const float* fW3 = (const float*)d_in[16];
    const float* fb3 = (const float*)d_in[17];
    const float* oW1 = (const float*)d_in[18];
    const float* ob1 = (const float*)d_in[19];
    const float* oW2 = (const float*)d_in[20];
    const float* ob2 = (const float*)d_in[21];
    float* out = (float*)d_out;

    char* ws = (char*)d_ws;
    size_t off = 0;
    auto alloc = [&](size_t bytes) -> void* {
        void* p = ws + off;
        off = (off + bytes + 255) & ~(size_t)255;
        return p;
    };
    typedef unsigned short bf_t;
    int* sen_cnt = (int*)alloc((size_t)NN * 4);
    int* sec_cnt = (int*)alloc((size_t)NN * 4);
    unsigned short* sen_idx = (unsigned short*)alloc((size_t)NN * MAXDEG * 2);
    unsigned short* sec_idx = (unsigned short*)alloc((size_t)NN * 8 * 2);
    float* g1buf = (float*)alloc((size_t)NN * DHID * 4);
    float* gl1   = (float*)alloc((size_t)NN * NHEADS * 4);
    float* gr1   = (float*)alloc((size_t)NN * NHEADS * 4);
    bf_t*  x1    = (bf_t*)alloc((size_t)NN * DHID * 2);
    float* g2buf = (float*)alloc((size_t)NN * DIN * 4);
    float* gl2   = (float*)alloc((size_t)NN * 4);
    float* gr2   = (float*)alloc((size_t)NN * 4);
    float* gmean = (float*)alloc((size_t)DHID * 4);
    bf_t*  fcat  = (bf_t*)alloc((size_t)NN * (2 * DIN) * 2);
    bf_t*  fbuf  = (bf_t*)alloc((size_t)NN * DIN * 2);
    bf_t*  tA    = (bf_t*)alloc((size_t)NN * DFFN * 2);
    bf_t*  tB    = (bf_t*)alloc((size_t)NN * DFFN * 2);
    bf_t*  featb = (bf_t*)alloc((size_t)NN * DIN * 2);
    bf_t* g1W1T = (bf_t*)alloc((size_t)DIN * DHID * 2);
    bf_t* g1W2T = (bf_t*)alloc((size_t)DHID * DIN * 2);
    bf_t* g2W1T = (bf_t*)alloc((size_t)DIN * DHID * 2);
    bf_t* g2W2T = (bf_t*)alloc((size_t)DHID * DIN * 2);
    bf_t* WfT   = (bf_t*)alloc((size_t)(2 * DIN) * DIN * 2);
    bf_t* fW1T  = (bf_t*)alloc((size_t)DIN * DFFN * 2);
    bf_t* fW2T  = (bf_t*)alloc((size_t)DFFN * DFFN * 2);
    bf_t* fW3T  = (bf_t*)alloc((size_t)DFFN * DIN * 2);
    bf_t* oW1T  = (bf_t*)alloc((size_t)DIN * DFFN * 2);
    bf_t* oW2T  = (bf_t*)alloc((size_t)DFFN * DIN * 2);

    // --- prep: neighbor lists, weight transposes, feature cast ---
    build_nbrs<<<NN, 256, 0, stream>>>(adj, sen_idx, sen_cnt, sec_idx, sec_cnt);
    auto tp = [&](const float* W, bf_t* WT, int K, int N) {
        transpose_cast<<<dim3(N / 32, K / 32), 256, 0, stream>>>(W, WT, K, N);
    };
    tp(g1W1, g1W1T, DIN, DHID);   tp(g1W2, g1W2T, DHID, DIN);
    tp(g2W1, g2W1T, DIN, DHID);   tp(g2W2, g2W2T, DHID, DIN);
    tp(Wf, WfT, 2 * DIN, DIN);
    tp(fW1, fW1T, DIN, DFFN);     tp(fW2, fW2T, DFFN, DFFN);
    tp(fW3, fW3T, DFFN, DIN);
    tp(oW1, oW1T, DIN, DFFN);     tp(oW2, oW2T, DFFN, DIN);
    cast_bf16<<<(NN * DIN) / 256, 256, 0, stream>>>(feature, featb, NN * DIN);

    auto run_gat = [&](const bf_t* W1T, const float* a1, const bf_t* W2T, const float* a2,
                       const unsigned short* idx, int idx_stride, const int* cnt, int coloff) {
        gemm_mfma<64, float><<<dim3(DHID / 64, NN / 128), 256, 0, stream>>>(
            featb, W1T, nullptr, nullptr, g1buf, NN, DHID, DIN, 0);
        glgr_kernel<<<NN * NHEADS, 64, 0, stream>>>(g1buf, a1, FPRIME, gl1, gr1);
        zero_f32<<<DHID / 256, 256, 0, stream>>>(gmean, DHID);
        col_mean<<<dim3(DHID / 256, 16), 256, 0, stream>>>(g1buf, DHID, gmean);
        attn_agg<NHEADS, FPRIME, bf_t><<<NN, 256, 0, stream>>>(
            g1buf, gl1, gr1, idx, idx_stride, cnt, gmean, x1, DHID, 0, nullptr, 0);
        gemm_mfma<64, float><<<dim3(DIN / 64, NN / 128), 256, 0, stream>>>(
            x1, W2T, nullptr, nullptr, g2buf, NN, DIN, DHID, 0);
        glgr_kernel<<<NN, 64, 0, stream>>>(g2buf, a2, DIN, gl2, gr2);
        zero_f32<<<DIN / 256, 256, 0, stream>>>(gmean, DIN);
        col_mean<<<dim3(DIN / 256, 16), 256, 0, stream>>>(g2buf, DIN, gmean);
        attn_agg<1, DIN, bf_t><<<NN, 256, 0, stream>>>(
            g2buf, gl2, gr2, idx, idx_stride, cnt, gmean, fcat, 2 * DIN, coloff, feature, 1);
    };

    run_gat(g1W1T, g1a1, g1W2T, g1a2, sen_idx, MAXDEG, sen_cnt, DIN);  // f_sen -> cols 768:1536
    run_gat(g2W1T, g2a1, g2W2T, g2a2, sec_idx, 8, sec_cnt, 0);         // f_sec -> cols 0:768

    gemm_mfma<64, bf_t><<<dim3(DIN / 64, NN / 128), 256, 0, stream>>>(
        fcat, WfT, bfv, nullptr, fbuf, NN, DIN, 2 * DIN, 1);
    gemm_mfma<128, bf_t><<<dim3(DFFN / 128, NN / 128), 256, 0, stream>>>(
        fbuf, fW1T, fb1, nullptr, tA, NN, DFFN, DIN, 1);
    gemm_mfma<128, bf_t><<<dim3(DFFN / 128, NN / 128), 256, 0, stream>>>(
        tA, fW2T, fb2, nullptr, tB, NN, DFFN, DFFN, 1);
    gemm_mfma<64, bf_t><<<dim3(DIN / 64, NN / 128), 256, 0, stream>>>(
        tB, fW3T, fb3, nullptr, fbuf, NN, DIN, DFFN, 1);
    gemm_mfma<128, bf_t><<<dim3(DFFN / 128, NN / 128), 256, 0, stream>>>(
        fbuf, oW1T, ob1, nullptr, tA, NN, DFFN, DIN, 1);
    gemm_mfma<64, float><<<dim3(DIN / 64, NN / 128), 256, 0, stream>>>(
        tA, oW2T, ob2, feature, out, NN, DIN, DFFN, 1);
}

// Round 4
// 626.004 us; speedup vs baseline: 2.2288x; 1.0477x over previous
//
#include <hip/hip_runtime.h>
#include <hip/hip_bf16.h>
#include <cmath>

#define NN 2048
#define DIN 768
#define DHID 1024
#define NHEADS 8
#define FPRIME 128
#define DFFN 2048
#define SEN_LIM 2042
#define MAXDEG 256

using short8 = __attribute__((ext_vector_type(8))) short;
using f32x4  = __attribute__((ext_vector_type(4))) float;

#if defined(__has_builtin)
#  if __has_builtin(__builtin_amdgcn_global_load_lds)
#    define HAVE_GLL 1
#  endif
#endif
#ifndef HAVE_GLL
#  define HAVE_GLL 0
#endif

__device__ inline unsigned short f2bf(float f) {
    unsigned u = __float_as_uint(f);
    unsigned r = u + 0x7FFFu + ((u >> 16) & 1u);   // RNE
    return (unsigned short)(r >> 16);
}
__device__ inline float bf2f(unsigned short h) {
    return __uint_as_float(((unsigned)h) << 16);
}
__device__ inline void store_out(float* p, float v) { *p = v; }
__device__ inline void store_out(unsigned short* p, float v) { *p = f2bf(v); }

#if HAVE_GLL
__device__ inline void gll16(const unsigned short* g, unsigned short* l) {
    __builtin_amdgcn_global_load_lds(
        (const __attribute__((address_space(1))) unsigned int*)g,
        (__attribute__((address_space(3))) unsigned int*)l, 16, 0, 0);
}
#endif

// ---------------------------------------------------------------------------
// Neighbor lists (sen: j<2042, capped 256; sec: j>=2042, capped 8)
// ---------------------------------------------------------------------------
__global__ __launch_bounds__(256) void build_nbrs(
    const float* __restrict__ adj,
    unsigned short* __restrict__ sen_idx, int* __restrict__ sen_cnt,
    unsigned short* __restrict__ sec_idx, int* __restrict__ sec_cnt)
{
    const int i = blockIdx.x;
    __shared__ int c_sen, c_sec;
    if (threadIdx.x == 0) { c_sen = 0; c_sec = 0; }
    __syncthreads();
    for (int j4 = threadIdx.x; j4 < NN / 4; j4 += 256) {
        float4 v = *(const float4*)&adj[(size_t)i * NN + j4 * 4];
        float vs[4] = {v.x, v.y, v.z, v.w};
        #pragma unroll
        for (int q = 0; q < 4; ++q) {
            if (vs[q] != 0.0f) {
                int j = j4 * 4 + q;
                if (j < SEN_LIM) {
                    int p = atomicAdd(&c_sen, 1);
                    if (p < MAXDEG) sen_idx[(size_t)i * MAXDEG + p] = (unsigned short)j;
                } else {
                    int p = atomicAdd(&c_sec, 1);
                    if (p < 8) sec_idx[i * 8 + p] = (unsigned short)j;
                }
            }
        }
    }
    __syncthreads();
    if (threadIdx.x == 0) { sen_cnt[i] = min(c_sen, MAXDEG); sec_cnt[i] = min(c_sec, 8); }
}

// ---------------------------------------------------------------------------
// Transpose + cast: W[K][N] f32 -> WT[N][K] bf16
// ---------------------------------------------------------------------------
__global__ __launch_bounds__(256) void transpose_cast(
    const float* __restrict__ W, unsigned short* __restrict__ WT, int K, int N)
{
    __shared__ float t[32][33];
    const int bn = blockIdx.x * 32, bk = blockIdx.y * 32;
    const int tx = threadIdx.x & 31, ty = threadIdx.x >> 5;
    #pragma unroll
    for (int r = 0; r < 4; ++r)
        t[ty + r * 8][tx] = W[(size_t)(bk + ty + r * 8) * N + bn + tx];
    __syncthreads();
    #pragma unroll
    for (int r = 0; r < 4; ++r) {
        int n = ty + r * 8;
        WT[(size_t)(bn + n) * K + bk + tx] = f2bf(t[tx][n]);
    }
}

__global__ __launch_bounds__(256) void cast_bf16(
    const float* __restrict__ in, unsigned short* __restrict__ out, int n)
{
    int t = blockIdx.x * 256 + threadIdx.x;
    if (t < n) out[t] = f2bf(in[t]);
}

__global__ __launch_bounds__(256) void zero_f32(float* p, int n)
{
    int t = blockIdx.x * 256 + threadIdx.x;
    if (t < n) p[t] = 0.f;
}

__global__ __launch_bounds__(256) void col_mean(
    const float* __restrict__ g, int C, float* __restrict__ out)
{
    int c = blockIdx.x * 256 + threadIdx.x;
    int r0 = blockIdx.y * 128;
    float s = 0.f;
    for (int r = r0; r < r0 + 128; ++r) s += g[(size_t)r * C + c];
    atomicAdd(&out[c], s * (1.0f / 2048.0f));
}

// ---------------------------------------------------------------------------
// bf16 MFMA GEMM, global_load_lds staging (m97 structure).
// C[M,N] = act(A@B + bias) (+resid); A bf16 [M][K], BT bf16 [N][K].
// BM=128, BK=64; 4 waves 2x2; optional second bf16 output Cb.
// ---------------------------------------------------------------------------
template<int BN, typename OUT_T>
__global__ __launch_bounds__(256) void gemm_mfma(
    const unsigned short* __restrict__ A, const unsigned short* __restrict__ BT,
    const float* __restrict__ bias, const float* __restrict__ resid,
    OUT_T* __restrict__ C, unsigned short* __restrict__ Cb,
    int M, int N, int K, int act)
{
    constexpr int BM = 128, BK = 64;
    constexpr int NF = BN / 32;              // N-frags per wave (4 or 2)
    __shared__ unsigned short Asm[BM * BK];
    __shared__ unsigned short Bsm[BN * BK];
    const int tid = threadIdx.x;
    const int lane = tid & 63, w = tid >> 6;
    const int wr = w >> 1, wc = w & 1;
    const int bm = blockIdx.y * BM, bn = blockIdx.x * BN;

    f32x4 acc[4][NF];
    #pragma unroll
    for (int mi = 0; mi < 4; ++mi)
        #pragma unroll
        for (int ni = 0; ni < NF; ++ni)
            acc[mi][ni] = (f32x4){0.f, 0.f, 0.f, 0.f};

    const unsigned short* Abase = A + (size_t)bm * K;
    const unsigned short* Bbase = BT + (size_t)bn * K;

    for (int k0 = 0; k0 < K; k0 += BK) {
        __syncthreads();                     // LDS safe to overwrite
        #pragma unroll
        for (int c = 0; c < 4; ++c) {        // A tile: 128x64 bf16 = 16KB
            int e = (tid + c * 256) * 8;
            int r = e >> 6, kk = e & 63;
#if HAVE_GLL
            gll16(&Abase[(size_t)r * K + k0 + kk], &Asm[e]);
#else
            *(short8*)&Asm[e] = *(const short8*)&Abase[(size_t)r * K + k0 + kk];
#endif
        }
        #pragma unroll
        for (int c = 0; c < NF; ++c) {       // B tile: BNx64 bf16
            int e = (tid + c * 256) * 8;
            int r = e >> 6, kk = e & 63;
#if HAVE_GLL
            gll16(&Bbase[(size_t)r * K + k0 + kk], &Bsm[e]);
#else
            *(short8*)&Bsm[e] = *(const short8*)&Bbase[(size_t)r * K + k0 + kk];
#endif
        }
        __syncthreads();                     // drains vmcnt before ds_read
        #pragma unroll
        for (int ks = 0; ks < 2; ++ks) {
            short8 af[4], bfv[NF];
            #pragma unroll
            for (int mi = 0; mi < 4; ++mi)
                af[mi] = *(const short8*)&Asm[(wr * 64 + mi * 16 + (lane & 15)) * 64
                                              + ks * 32 + (lane >> 4) * 8];
            #pragma unroll
            for (int ni = 0; ni < NF; ++ni)
                bfv[ni] = *(const short8*)&Bsm[(wc * (BN / 2) + ni * 16 + (lane & 15)) * 64
                                               + ks * 32 + (lane >> 4) * 8];
            #pragma unroll
            for (int mi = 0; mi < 4; ++mi)
                #pragma unroll
                for (int ni = 0; ni < NF; ++ni)
                    acc[mi][ni] = __builtin_amdgcn_mfma_f32_16x16x32_bf16(
                        af[mi], bfv[ni], acc[mi][ni], 0, 0, 0);
        }
    }

    const int rbase = bm + wr * 64;
    const int cbase = bn + wc * (BN / 2);
    #pragma unroll
    for (int mi = 0; mi < 4; ++mi)
        #pragma unroll
        for (int ni = 0; ni < NF; ++ni)
            #pragma unroll
            for (int r = 0; r < 4; ++r) {
                int grow = rbase + mi * 16 + (lane >> 4) * 4 + r;
                int gcol = cbase + ni * 16 + (lane & 15);
                float v = acc[mi][ni][r];
                if (bias)  v += bias[gcol];
                if (act)   v = (v >= 0.f) ? v : 0.01f * v;
                if (resid) v += resid[(size_t)grow * N + gcol];
                store_out(&C[(size_t)grow * N + gcol], v);
                if (Cb) Cb[(size_t)grow * N + gcol] = f2bf(v);
            }
}

// ---------------------------------------------------------------------------
// gl/gr dot products (g f32)
// ---------------------------------------------------------------------------
__global__ __launch_bounds__(64) void glgr_kernel(
    const float* __restrict__ g, const float* __restrict__ a,
    int F, float* __restrict__ gl, float* __restrict__ gr)
{
    const int b = blockIdx.x;
    const int lane = threadIdx.x;
    const float* gb = g + (size_t)b * F;
    float sl = 0.f, sr = 0.f;
    for (int f = lane; f < F; f += 64) {
        float v = gb[f];
        sl += v * a[f];
        sr += v * a[F + f];
    }
    #pragma unroll
    for (int off = 32; off > 0; off >>= 1) {
        sl += __shfl_down(sl, off);
        sr += __shfl_down(sr, off);
    }
    if (lane == 0) { gl[b] = sl; gr[b] = sr; }
}

// ---------------------------------------------------------------------------
// Sparse GAT attention+aggregation. Wave-shuffle score reductions; pass-3
// gathers bf16 g rows, 4 consecutive cols/thread (ushort4 = 8B/lane).
// mode 0: ELU epilogue; mode 1: += resid.
// ---------------------------------------------------------------------------
template<int H, int F, typename OUT_T>
__global__ __launch_bounds__(256) void attn_agg(
    const float* __restrict__ g,            // [NN, H*F] f32 (scores)
    const unsigned short* __restrict__ gb,  // [NN, H*F] bf16 (gather)
    const float* __restrict__ gl,
    const float* __restrict__ gr,
    const unsigned short* __restrict__ idx, int idx_stride,
    const int* __restrict__ cnt,
    const float* __restrict__ gmean,
    OUT_T* __restrict__ dst, int dst_stride, int dst_coloff,
    const float* __restrict__ resid, int mode)
{
    constexpr int HF = H * F;
    const int i = blockIdx.x;
    const int tid = threadIdx.x;
    const int lane = tid & 63, w = tid >> 6;
    const int n = cnt[i];

    if (n == 0) {
        for (int c = tid; c < HF; c += 256) {
            float v = gmean[c];
            if (mode == 0) v = (v > 0.f) ? v : expm1f(v);
            else           v += resid[(size_t)i * HF + c];
            store_out(&dst[(size_t)i * dst_stride + dst_coloff + c], v);
        }
        return;
    }

    __shared__ float s_wred[4 * H];
    __shared__ float s_max[H], s_inv[H], s_glh[H];
    __shared__ float s_w[128 * H];
    __shared__ unsigned short s_j[128];

    if (tid < H) s_glh[tid] = gl[(size_t)i * H + tid];
    __syncthreads();
    float glh[H];
    #pragma unroll
    for (int h = 0; h < H; ++h) glh[h] = s_glh[h];

    const unsigned short* row_idx = idx + (size_t)i * idx_stride;

    // Pass 1: per-head max
    float pmax[H];
    #pragma unroll
    for (int h = 0; h < H; ++h) pmax[h] = -1e30f;
    for (int jj = tid; jj < n; jj += 256) {
        int j = row_idx[jj];
        if (H == 8) {
            float4 ga = *(const float4*)&gr[(size_t)j * 8];
            float4 gbv = *(const float4*)&gr[(size_t)j * 8 + 4];
            float sc[8] = {ga.x, ga.y, ga.z, ga.w, gbv.x, gbv.y, gbv.z, gbv.w};
            #pragma unroll
            for (int h = 0; h < H; ++h) {
                float s = glh[h] + sc[h];
                s = (s >= 0.f) ? s : 0.2f * s;
                pmax[h] = fmaxf(pmax[h], s);
            }
        } else {
            float s = glh[0] + gr[j];
            s = (s >= 0.f) ? s : 0.2f * s;
            pmax[0] = fmaxf(pmax[0], s);
        }
    }
    #pragma unroll
    for (int h = 0; h < H; ++h)
        #pragma unroll
        for (int off = 32; off > 0; off >>= 1)
            pmax[h] = fmaxf(pmax[h], __shfl_xor(pmax[h], off));
    if (lane == 0)
        #pragma unroll
        for (int h = 0; h < H; ++h) s_wred[w * H + h] = pmax[h];
    __syncthreads();
    if (tid < H)
        s_max[tid] = fmaxf(fmaxf(s_wred[tid], s_wred[H + tid]),
                           fmaxf(s_wred[2 * H + tid], s_wred[3 * H + tid]));
    __syncthreads();
    float mx[H];
    #pragma unroll
    for (int h = 0; h < H; ++h) mx[h] = s_max[h];

    // Pass 2: per-head exp-sum
    float psum[H];
    #pragma unroll
    for (int h = 0; h < H; ++h) psum[h] = 0.f;
    for (int jj = tid; jj < n; jj += 256) {
        int j = row_idx[jj];
        if (H == 8) {
            float4 ga = *(const float4*)&gr[(size_t)j * 8];
            float4 gbv = *(const float4*)&gr[(size_t)j * 8 + 4];
            float sc[8] = {ga.x, ga.y, ga.z, ga.w, gbv.x, gbv.y, gbv.z, gbv.w};
            #pragma unroll
            for (int h = 0; h < H; ++h) {
                float s = glh[h] + sc[h];
                s = (s >= 0.f) ? s : 0.2f * s;
                psum[h] += expf(s - mx[h]);
            }
        } else {
            float s = glh[0] + gr[j];
            s = (s >= 0.f) ? s : 0.2f * s;
            psum[0] += expf(s - mx[0]);
        }
    }
    #pragma unroll
    for (int h = 0; h < H; ++h)
        #pragma unroll
        for (int off = 32; off > 0; off >>= 1)
            psum[h] += __shfl_xor(psum[h], off);
    if (lane == 0)
        #pragma unroll
        for (int h = 0; h < H; ++h) s_wred[w * H + h] = psum[h];
    __syncthreads();
    if (tid < H)
        s_inv[tid] = 1.f / (s_wred[tid] + s_wred[H + tid] +
                            s_wred[2 * H + tid] + s_wred[3 * H + tid]);
    // (ordering barrier supplied by first pass-3 iteration)

    // Pass 3: bf16 gather, 4 consecutive cols per thread
    const int cb = tid * 4;
    const bool active = (cb < HF);
    const int hh = (H == 8) ? (cb >> 7) : 0;
    float a0 = 0.f, a1 = 0.f, a2 = 0.f, a3 = 0.f;

    for (int c0 = 0; c0 < n; c0 += 128) {
        int m = min(128, n - c0);
        __syncthreads();
        for (int e = tid; e < m * H; e += 256) {
            int jj = (H == 8) ? (e >> 3) : e;
            int h  = (H == 8) ? (e & 7) : 0;
            int j = row_idx[c0 + jj];
            float s = glh[h] + gr[(size_t)j * H + h];
            s = (s >= 0.f) ? s : 0.2f * s;
            s_w[jj * H + h] = expf(s - s_max[h]) * s_inv[h];
            if (h == 0) s_j[jj] = (unsigned short)j;
        }
        __syncthreads();
        if (active) {
            int jj = 0;
            for (; jj + 4 <= m; jj += 4) {
                ushort4 v0 = *(const ushort4*)&gb[(size_t)s_j[jj]     * HF + cb];
                ushort4 v1 = *(const ushort4*)&gb[(size_t)s_j[jj + 1] * HF + cb];
                ushort4 v2 = *(const ushort4*)&gb[(size_t)s_j[jj + 2] * HF + cb];
                ushort4 v3 = *(const ushort4*)&gb[(size_t)s_j[jj + 3] * HF + cb];
                float w0 = s_w[jj * H + hh], w1 = s_w[(jj + 1) * H + hh];
                float w2 = s_w[(jj + 2) * H + hh], w3 = s_w[(jj + 3) * H + hh];
                a0 += w0 * bf2f(v0.x) + w1 * bf2f(v1.x) + w2 * bf2f(v2.x) + w3 * bf2f(v3.x);
                a1 += w0 * bf2f(v0.y) + w1 * bf2f(v1.y) + w2 * bf2f(v2.y) + w3 * bf2f(v3.y);
                a2 += w0 * bf2f(v0.z) + w1 * bf2f(v1.z) + w2 * bf2f(v2.z) + w3 * bf2f(v3.z);
                a3 += w0 * bf2f(v0.w) + w1 * bf2f(v1.w) + w2 * bf2f(v2.w) + w3 * bf2f(v3.w);
            }
            for (; jj < m; ++jj) {
                ushort4 v0 = *(const ushort4*)&gb[(size_t)s_j[jj] * HF + cb];
                float w0 = s_w[jj * H + hh];
                a0 += w0 * bf2f(v0.x); a1 += w0 * bf2f(v0.y);
                a2 += w0 * bf2f(v0.z); a3 += w0 * bf2f(v0.w);
            }
        }
    }

    if (active) {
        float vv[4] = {a0, a1, a2, a3};
        #pragma unroll
        for (int q = 0; q < 4; ++q) {
            float v = vv[q];
            if (mode == 0) v = (v > 0.f) ? v : expm1f(v);
            else           v += resid[(size_t)i * HF + cb + q];
            store_out(&dst[(size_t)i * dst_stride + dst_coloff + cb + q], v);
        }
    }
}

// ---------------------------------------------------------------------------
extern "C" void kernel_launch(void* const* d_in, const int* in_sizes, int n_in,
                              void* d_out, int out_size, void* d_ws, size_t ws_size,
                              hipStream_t stream)
{
    const float* feature = (const float*)d_in[0];
    const float* adj     = (const float*)d_in[1];
    const float* g1W1 = (const float*)d_in[2];
    const float* g1a1 = (const float*)d_in[3];
    const float* g1W2 = (const float*)d_in[4];
    const float* g1a2 = (const float*)d_in[5];
    const float* g2W1 = (const float*)d_in[6];
    const float* g2a1 = (const float*)d_in[7];
    const float* g2W2 = (const float*)d_in[8];
    const float* g2a2 = (const float*)d_in[9];
    const float* Wf  = (const float*)d_in[10];
    const float* bfv = (const float*)d_in[11];
    const float* fW1 = (const float*)d_in[12];
    const float* fb1 = (const float*)d_in[13];
    const float* fW2 = (const float*)d_in[14];
    const float* fb2 = (const float*)d_in[15];
    const float* fW3 = (const float*)d_in[16];
    const float* fb3 = (const float*)d_in[17];
    const float* oW1 = (const float*)d_in[18];
    const float* ob1 = (const float*)d_in[19];
    const float* oW2 = (const float*)d_in[20];
    const float* ob2 = (const float*)d_in[21];
    float* out = (float*)d_out;

    char* ws = (char*)d_ws;
    size_t off = 0;
    auto alloc = [&](size_t bytes) -> void* {
        void* p = ws + off;
        off = (off + bytes + 255) & ~(size_t)255;
        return p;
    };
    typedef unsigned short bf_t;
    int* sen_cnt = (int*)alloc((size_t)NN * 4);
    int* sec_cnt = (int*)alloc((size_t)NN * 4);
    unsigned short* sen_idx = (unsigned short*)alloc((size_t)NN * MAXDEG * 2);
    unsigned short* sec_idx = (unsigned short*)alloc((size_t)NN * 8 * 2);
    float* g1buf = (float*)alloc((size_t)NN * DHID * 4);
    bf_t*  g1b   = (bf_t*)alloc((size_t)NN * DHID * 2);
    float* gl1   = (float*)alloc((size_t)NN * NHEADS * 4);
    float* gr1   = (float*)alloc((size_t)NN * NHEADS * 4);
    bf_t*  x1    = (bf_t*)alloc((size_t)NN * DHID * 2);
    float* g2buf = (float*)alloc((size_t)NN * DIN * 4);
    bf_t*  g2b   = (bf_t*)alloc((size_t)NN * DIN * 2);
    float* gl2   = (float*)alloc((size_t)NN * 4);
    float* gr2   = (float*)alloc((size_t)NN * 4);
    float* gmean = (float*)alloc((size_t)DHID * 4);
    bf_t*  fcat  = (bf_t*)alloc((size_t)NN * (2 * DIN) * 2);
    bf_t*  fbuf  = (bf_t*)alloc((size_t)NN * DIN * 2);
    bf_t*  tA    = (bf_t*)alloc((size_t)NN * DFFN * 2);
    bf_t*  tB    = (bf_t*)alloc((size_t)NN * DFFN * 2);
    bf_t*  featb = (bf_t*)alloc((size_t)NN * DIN * 2);
    bf_t* g1W1T = (bf_t*)alloc((size_t)DIN * DHID * 2);
    bf_t* g1W2T = (bf_t*)alloc((size_t)DHID * DIN * 2);
    bf_t* g2W1T = (bf_t*)alloc((size_t)DIN * DHID * 2);
    bf_t* g2W2T = (bf_t*)alloc((size_t)DHID * DIN * 2);
    bf_t* WfT   = (bf_t*)alloc((size_t)(2 * DIN) * DIN * 2);
    bf_t* fW1T  = (bf_t*)alloc((size_t)DIN * DFFN * 2);
    bf_t* fW2T  = (bf_t*)alloc((size_t)DFFN * DFFN * 2);
    bf_t* fW3T  = (bf_t*)alloc((size_t)DFFN * DIN * 2);
    bf_t* oW1T  = (bf_t*)alloc((size_t)DIN * DFFN * 2);
    bf_t* oW2T  = (bf_t*)alloc((size_t)DFFN * DIN * 2);

    build_nbrs<<<NN, 256, 0, stream>>>(adj, sen_idx, sen_cnt, sec_idx, sec_cnt);
    auto tp = [&](const float* W, bf_t* WT, int K, int N) {
        transpose_cast<<<dim3(N / 32, K / 32), 256, 0, stream>>>(W, WT, K, N);
    };
    tp(g1W1, g1W1T, DIN, DHID);   tp(g1W2, g1W2T, DHID, DIN);
    tp(g2W1, g2W1T, DIN, DHID);   tp(g2W2, g2W2T, DHID, DIN);
    tp(Wf, WfT, 2 * DIN, DIN);
    tp(fW1, fW1T, DIN, DFFN);     tp(fW2, fW2T, DFFN, DFFN);
    tp(fW3, fW3T, DFFN, DIN);
    tp(oW1, oW1T, DIN, DFFN);     tp(oW2, oW2T, DFFN, DIN);
    cast_bf16<<<(NN * DIN) / 256, 256, 0, stream>>>(feature, featb, NN * DIN);

    auto run_gat = [&](const bf_t* W1T, const float* a1, const bf_t* W2T, const float* a2,
                       const unsigned short* idx, int idx_stride, const int* cnt, int coloff) {
        gemm_mfma<64, float><<<dim3(DHID / 64, NN / 128), 256, 0, stream>>>(
            featb, W1T, nullptr, nullptr, g1buf, g1b, NN, DHID, DIN, 0);
        glgr_kernel<<<NN * NHEADS, 64, 0, stream>>>(g1buf, a1, FPRIME, gl1, gr1);
        zero_f32<<<DHID / 256, 256, 0, stream>>>(gmean, DHID);
        col_mean<<<dim3(DHID / 256, 16), 256, 0, stream>>>(g1buf, DHID, gmean);
        attn_agg<NHEADS, FPRIME, bf_t><<<NN, 256, 0, stream>>>(
            g1buf, g1b, gl1, gr1, idx, idx_stride, cnt, gmean, x1, DHID, 0, nullptr, 0);
        gemm_mfma<64, float><<<dim3(DIN / 64, NN / 128), 256, 0, stream>>>(
            x1, W2T, nullptr, nullptr, g2buf, g2b, NN, DIN, DHID, 0);
        glgr_kernel<<<NN, 64, 0, stream>>>(g2buf, a2, DIN, gl2, gr2);
        zero_f32<<<DIN / 256, 256, 0, stream>>>(gmean, DIN);
        col_mean<<<dim3(DIN / 256, 16), 256, 0, stream>>>(g2buf, DIN, gmean);
        attn_agg<1, DIN, bf_t><<<NN, 256, 0, stream>>>(
            g2buf, g2b, gl2, gr2, idx, idx_stride, cnt, gmean, fcat, 2 * DIN, coloff, feature, 1);
    };

    run_gat(g1W1T, g1a1, g1W2T, g1a2, sen_idx, MAXDEG, sen_cnt, DIN);  // f_sen -> cols 768:1536
    run_gat(g2W1T, g2a1, g2W2T, g2a2, sec_idx, 8, sec_cnt, 0);         // f_sec -> cols 0:768

    gemm_mfma<64, bf_t><<<dim3(DIN / 64, NN / 128), 256, 0, stream>>>(
        fcat, WfT, bfv, nullptr, fbuf, nullptr, NN, DIN, 2 * DIN, 1);
    gemm_mfma<128, bf_t><<<dim3(DFFN / 128, NN / 128), 256, 0, stream>>>(
        fbuf, fW1T, fb1, nullptr, tA, nullptr, NN, DFFN, DIN, 1);
    gemm_mfma<128, bf_t><<<dim3(DFFN / 128, NN / 128), 256, 0, stream>>>(
        tA, fW2T, fb2, nullptr, tB, nullptr, NN, DFFN, DFFN, 1);
    gemm_mfma<64, bf_t><<<dim3(DIN / 64, NN / 128), 256, 0, stream>>>(
        tB, fW3T, fb3, nullptr, fbuf, nullptr, NN, DIN, DFFN, 1);
    gemm_mfma<128, bf_t><<<dim3(DFFN / 128, NN / 128), 256, 0, stream>>>(
        fbuf, oW1T, ob1, nullptr, tA, nullptr, NN, DFFN, DIN, 1);
    gemm_mfma<64, float><<<dim3(DIN / 64, NN / 128), 256, 0, stream>>>(
        tA, oW2T, ob2, feature, out, nullptr, NN, DIN, DFFN, 1);
}

// Round 5
// 522.205 us; speedup vs baseline: 2.6719x; 1.1988x over previous
//
#include <hip/hip_runtime.h>
#include <hip/hip_bf16.h>
#include <cmath>

#define NN 2048
#define DIN 768
#define DHID 1024
#define NHEADS 8
#define FPRIME 128
#define DFFN 2048
#define SEN_LIM 2042
#define MAXDEG 256

using short8 = __attribute__((ext_vector_type(8))) short;
using f32x4  = __attribute__((ext_vector_type(4))) float;

#if defined(__has_builtin)
#  if __has_builtin(__builtin_amdgcn_global_load_lds)
#    define HAVE_GLL 1
#  endif
#endif
#ifndef HAVE_GLL
#  define HAVE_GLL 0
#endif

__device__ inline unsigned short f2bf(float f) {
    unsigned u = __float_as_uint(f);
    unsigned r = u + 0x7FFFu + ((u >> 16) & 1u);   // RNE
    return (unsigned short)(r >> 16);
}
__device__ inline float bf2f(unsigned short h) {
    return __uint_as_float(((unsigned)h) << 16);
}
__device__ inline void store_out(float* p, float v) { *p = v; }
__device__ inline void store_out(unsigned short* p, float v) { *p = f2bf(v); }

#if HAVE_GLL
__device__ inline void gll16(const unsigned short* g, unsigned short* l) {
    __builtin_amdgcn_global_load_lds(
        (const __attribute__((address_space(1))) unsigned int*)g,
        (__attribute__((address_space(3))) unsigned int*)l, 16, 0, 0);
}
#endif

// ---------------------------------------------------------------------------
// Neighbor lists (sen: j<2042, capped 256; sec: j>=2042, capped 8)
// ---------------------------------------------------------------------------
__global__ __launch_bounds__(256) void build_nbrs(
    const float* __restrict__ adj,
    unsigned short* __restrict__ sen_idx, int* __restrict__ sen_cnt,
    unsigned short* __restrict__ sec_idx, int* __restrict__ sec_cnt)
{
    const int i = blockIdx.x;
    __shared__ int c_sen, c_sec;
    if (threadIdx.x == 0) { c_sen = 0; c_sec = 0; }
    __syncthreads();
    for (int j4 = threadIdx.x; j4 < NN / 4; j4 += 256) {
        float4 v = *(const float4*)&adj[(size_t)i * NN + j4 * 4];
        float vs[4] = {v.x, v.y, v.z, v.w};
        #pragma unroll
        for (int q = 0; q < 4; ++q) {
            if (vs[q] != 0.0f) {
                int j = j4 * 4 + q;
                if (j < SEN_LIM) {
                    int p = atomicAdd(&c_sen, 1);
                    if (p < MAXDEG) sen_idx[(size_t)i * MAXDEG + p] = (unsigned short)j;
                } else {
                    int p = atomicAdd(&c_sec, 1);
                    if (p < 8) sec_idx[i * 8 + p] = (unsigned short)j;
                }
            }
        }
    }
    __syncthreads();
    if (threadIdx.x == 0) { sen_cnt[i] = min(c_sen, MAXDEG); sec_cnt[i] = min(c_sec, 8); }
}

// ---------------------------------------------------------------------------
// Transpose + cast: W[K][N] f32 -> WT[N][K] bf16
// ---------------------------------------------------------------------------
__global__ __launch_bounds__(256) void transpose_cast(
    const float* __restrict__ W, unsigned short* __restrict__ WT, int K, int N)
{
    __shared__ float t[32][33];
    const int bn = blockIdx.x * 32, bk = blockIdx.y * 32;
    const int tx = threadIdx.x & 31, ty = threadIdx.x >> 5;
    #pragma unroll
    for (int r = 0; r < 4; ++r)
        t[ty + r * 8][tx] = W[(size_t)(bk + ty + r * 8) * N + bn + tx];
    __syncthreads();
    #pragma unroll
    for (int r = 0; r < 4; ++r) {
        int n = ty + r * 8;
        WT[(size_t)(bn + n) * K + bk + tx] = f2bf(t[tx][n]);
    }
}

__global__ __launch_bounds__(256) void cast_bf16(
    const float* __restrict__ in, unsigned short* __restrict__ out, int n)
{
    int t = blockIdx.x * 256 + threadIdx.x;
    if (t < n) out[t] = f2bf(in[t]);
}

__global__ __launch_bounds__(256) void zero_f32(float* p, int n)
{
    int t = blockIdx.x * 256 + threadIdx.x;
    if (t < n) p[t] = 0.f;
}

__global__ __launch_bounds__(256) void col_mean(
    const float* __restrict__ g, int C, float* __restrict__ out)
{
    int c = blockIdx.x * 256 + threadIdx.x;
    int r0 = blockIdx.y * 128;
    float s = 0.f;
    for (int r = r0; r < r0 + 128; ++r) s += g[(size_t)r * C + c];
    atomicAdd(&out[c], s * (1.0f / 2048.0f));
}

// ---------------------------------------------------------------------------
// bf16 MFMA GEMM with XOR-swizzled LDS (T2, both-sides: pre-swizzled global
// source for linear global_load_lds dest + swizzled ds_read).
// C[M,N] = act(A@B + bias) (+resid); A bf16 [M][K], BT bf16 [N][K].
// BK=64. 4 waves: (BM/64) x (4/(BM/64)); per-wave 64 rows x BN/WC cols.
// ---------------------------------------------------------------------------
template<int BM, int BN, typename OUT_T>
__global__ __launch_bounds__(256) void gemm_mfma(
    const unsigned short* __restrict__ A, const unsigned short* __restrict__ BT,
    const float* __restrict__ bias, const float* __restrict__ resid,
    OUT_T* __restrict__ C, unsigned short* __restrict__ Cb,
    int M, int N, int K, int act)
{
    constexpr int BK = 64;
    constexpr int WR = BM / 64;          // wave-rows (1 or 2)
    constexpr int WC = 4 / WR;           // wave-cols (4 or 2)
    constexpr int NF = BN / (WC * 16);   // 16-col frags per wave
    constexpr int ACH = BM / 32;         // A staging chunks (256 thr x 8 elem)
    constexpr int BCH = BN / 32;
    __shared__ unsigned short Asm[BM * BK];
    __shared__ unsigned short Bsm[BN * BK];
    const int tid = threadIdx.x;
    const int lane = tid & 63, w = tid >> 6;
    const int wr = w / WC, wc = w % WC;
    const int bm = blockIdx.y * BM, bn = blockIdx.x * BN;

    f32x4 acc[4][NF];
    #pragma unroll
    for (int mi = 0; mi < 4; ++mi)
        #pragma unroll
        for (int ni = 0; ni < NF; ++ni)
            acc[mi][ni] = (f32x4){0.f, 0.f, 0.f, 0.f};

    const unsigned short* Abase = A + (size_t)bm * K;
    const unsigned short* Bbase = BT + (size_t)bn * K;

    for (int k0 = 0; k0 < K; k0 += BK) {
        __syncthreads();                     // LDS safe to overwrite
        #pragma unroll
        for (int c = 0; c < ACH; ++c) {      // A tile: BM x 64 bf16
            int e = (tid + c * 256) * 8;
            int r = e >> 6, kk = e & 63;
            int kks = kk ^ ((r & 7) << 3);   // pre-swizzled source col
#if HAVE_GLL
            gll16(&Abase[(size_t)r * K + k0 + kks], &Asm[e]);
#else
            *(short8*)&Asm[e] = *(const short8*)&Abase[(size_t)r * K + k0 + kks];
#endif
        }
        #pragma unroll
        for (int c = 0; c < BCH; ++c) {      // B tile: BN x 64 bf16
            int e = (tid + c * 256) * 8;
            int r = e >> 6, kk = e & 63;
            int kks = kk ^ ((r & 7) << 3);
#if HAVE_GLL
            gll16(&Bbase[(size_t)r * K + k0 + kks], &Bsm[e]);
#else
            *(short8*)&Bsm[e] = *(const short8*)&Bbase[(size_t)r * K + k0 + kks];
#endif
        }
        __syncthreads();                     // drains vmcnt before ds_read
        #pragma unroll
        for (int ks = 0; ks < 2; ++ks) {
            short8 af[4], bfv[NF];
            #pragma unroll
            for (int mi = 0; mi < 4; ++mi) {
                int row = wr * 64 + mi * 16 + (lane & 15);
                int col = (ks * 32 + (lane >> 4) * 8) ^ ((row & 7) << 3);
                af[mi] = *(const short8*)&Asm[row * 64 + col];
            }
            #pragma unroll
            for (int ni = 0; ni < NF; ++ni) {
                int row = wc * (BN / WC) + ni * 16 + (lane & 15);
                int col = (ks * 32 + (lane >> 4) * 8) ^ ((row & 7) << 3);
                bfv[ni] = *(const short8*)&Bsm[row * 64 + col];
            }
            #pragma unroll
            for (int mi = 0; mi < 4; ++mi)
                #pragma unroll
                for (int ni = 0; ni < NF; ++ni)
                    acc[mi][ni] = __builtin_amdgcn_mfma_f32_16x16x32_bf16(
                        af[mi], bfv[ni], acc[mi][ni], 0, 0, 0);
        }
    }

    const int rbase = bm + wr * 64;
    const int cbase = bn + wc * (BN / WC);
    #pragma unroll
    for (int mi = 0; mi < 4; ++mi)
        #pragma unroll
        for (int ni = 0; ni < NF; ++ni)
            #pragma unroll
            for (int r = 0; r < 4; ++r) {
                int grow = rbase + mi * 16 + (lane >> 4) * 4 + r;
                int gcol = cbase + ni * 16 + (lane & 15);
                float v = acc[mi][ni][r];
                if (bias)  v += bias[gcol];
                if (act)   v = (v >= 0.f) ? v : 0.01f * v;
                if (resid) v += resid[(size_t)grow * N + gcol];
                store_out(&C[(size_t)grow * N + gcol], v);
                if (Cb) Cb[(size_t)grow * N + gcol] = f2bf(v);
            }
}

// ---------------------------------------------------------------------------
// gl/gr dot products (g f32)
// ---------------------------------------------------------------------------
__global__ __launch_bounds__(64) void glgr_kernel(
    const float* __restrict__ g, const float* __restrict__ a,
    int F, float* __restrict__ gl, float* __restrict__ gr)
{
    const int b = blockIdx.x;
    const int lane = threadIdx.x;
    const float* gb = g + (size_t)b * F;
    float sl = 0.f, sr = 0.f;
    for (int f = lane; f < F; f += 64) {
        float v = gb[f];
        sl += v * a[f];
        sr += v * a[F + f];
    }
    #pragma unroll
    for (int off = 32; off > 0; off >>= 1) {
        sl += __shfl_down(sl, off);
        sr += __shfl_down(sr, off);
    }
    if (lane == 0) { gl[b] = sl; gr[b] = sr; }
}

// ---------------------------------------------------------------------------
// Sparse GAT attention+aggregation. Wave-shuffle score reductions; pass-3
// gathers bf16 g rows, 4 consecutive cols/thread (ushort4 = 8B/lane).
// mode 0: ELU epilogue; mode 1: += resid.
// ---------------------------------------------------------------------------
template<int H, int F, typename OUT_T>
__global__ __launch_bounds__(256) void attn_agg(
    const float* __restrict__ g,            // [NN, H*F] f32 (scores)
    const unsigned short* __restrict__ gb,  // [NN, H*F] bf16 (gather)
    const float* __restrict__ gl,
    const float* __restrict__ gr,
    const unsigned short* __restrict__ idx, int idx_stride,
    const int* __restrict__ cnt,
    const float* __restrict__ gmean,
    OUT_T* __restrict__ dst, int dst_stride, int dst_coloff,
    const float* __restrict__ resid, int mode)
{
    constexpr int HF = H * F;
    const int i = blockIdx.x;
    const int tid = threadIdx.x;
    const int lane = tid & 63, w = tid >> 6;
    const int n = cnt[i];

    if (n == 0) {
        for (int c = tid; c < HF; c += 256) {
            float v = gmean[c];
            if (mode == 0) v = (v > 0.f) ? v : expm1f(v);
            else           v += resid[(size_t)i * HF + c];
            store_out(&dst[(size_t)i * dst_stride + dst_coloff + c], v);
        }
        return;
    }

    __shared__ float s_wred[4 * H];
    __shared__ float s_max[H], s_inv[H], s_glh[H];
    __shared__ float s_w[128 * H];
    __shared__ unsigned short s_j[128];

    if (tid < H) s_glh[tid] = gl[(size_t)i * H + tid];
    __syncthreads();
    float glh[H];
    #pragma unroll
    for (int h = 0; h < H; ++h) glh[h] = s_glh[h];

    const unsigned short* row_idx = idx + (size_t)i * idx_stride;

    // Pass 1: per-head max
    float pmax[H];
    #pragma unroll
    for (int h = 0; h < H; ++h) pmax[h] = -1e30f;
    for (int jj = tid; jj < n; jj += 256) {
        int j = row_idx[jj];
        if (H == 8) {
            float4 ga = *(const float4*)&gr[(size_t)j * 8];
            float4 gbv = *(const float4*)&gr[(size_t)j * 8 + 4];
            float sc[8] = {ga.x, ga.y, ga.z, ga.w, gbv.x, gbv.y, gbv.z, gbv.w};
            #pragma unroll
            for (int h = 0; h < H; ++h) {
                float s = glh[h] + sc[h];
                s = (s >= 0.f) ? s : 0.2f * s;
                pmax[h] = fmaxf(pmax[h], s);
            }
        } else {
            float s = glh[0] + gr[j];
            s = (s >= 0.f) ? s : 0.2f * s;
            pmax[0] = fmaxf(pmax[0], s);
        }
    }
    #pragma unroll
    for (int h = 0; h < H; ++h)
        #pragma unroll
        for (int off = 32; off > 0; off >>= 1)
            pmax[h] = fmaxf(pmax[h], __shfl_xor(pmax[h], off));
    if (lane == 0)
        #pragma unroll
        for (int h = 0; h < H; ++h) s_wred[w * H + h] = pmax[h];
    __syncthreads();
    if (tid < H)
        s_max[tid] = fmaxf(fmaxf(s_wred[tid], s_wred[H + tid]),
                           fmaxf(s_wred[2 * H + tid], s_wred[3 * H + tid]));
    __syncthreads();
    float mx[H];
    #pragma unroll
    for (int h = 0; h < H; ++h) mx[h] = s_max[h];

    // Pass 2: per-head exp-sum
    float psum[H];
    #pragma unroll
    for (int h = 0; h < H; ++h) psum[h] = 0.f;
    for (int jj = tid; jj < n; jj += 256) {
        int j = row_idx[jj];
        if (H == 8) {
            float4 ga = *(const float4*)&gr[(size_t)j * 8];
            float4 gbv = *(const float4*)&gr[(size_t)j * 8 + 4];
            float sc[8] = {ga.x, ga.y, ga.z, ga.w, gbv.x, gbv.y, gbv.z, gbv.w};
            #pragma unroll
            for (int h = 0; h < H; ++h) {
                float s = glh[h] + sc[h];
                s = (s >= 0.f) ? s : 0.2f * s;
                psum[h] += expf(s - mx[h]);
            }
        } else {
            float s = glh[0] + gr[j];
            s = (s >= 0.f) ? s : 0.2f * s;
            psum[0] += expf(s - mx[0]);
        }
    }
    #pragma unroll
    for (int h = 0; h < H; ++h)
        #pragma unroll
        for (int off = 32; off > 0; off >>= 1)
            psum[h] += __shfl_xor(psum[h], off);
    if (lane == 0)
        #pragma unroll
        for (int h = 0; h < H; ++h) s_wred[w * H + h] = psum[h];
    __syncthreads();
    if (tid < H)
        s_inv[tid] = 1.f / (s_wred[tid] + s_wred[H + tid] +
                            s_wred[2 * H + tid] + s_wred[3 * H + tid]);
    // (ordering barrier supplied by first pass-3 iteration)

    // Pass 3: bf16 gather, 4 consecutive cols per thread
    const int cb = tid * 4;
    const bool active = (cb < HF);
    const int hh = (H == 8) ? (cb >> 7) : 0;
    float a0 = 0.f, a1 = 0.f, a2 = 0.f, a3 = 0.f;

    for (int c0 = 0; c0 < n; c0 += 128) {
        int m = min(128, n - c0);
        __syncthreads();
        for (int e = tid; e < m * H; e += 256) {
            int jj = (H == 8) ? (e >> 3) : e;
            int h  = (H == 8) ? (e & 7) : 0;
            int j = row_idx[c0 + jj];
            float s = glh[h] + gr[(size_t)j * H + h];
            s = (s >= 0.f) ? s : 0.2f * s;
            s_w[jj * H + h] = expf(s - s_max[h]) * s_inv[h];
            if (h == 0) s_j[jj] = (unsigned short)j;
        }
        __syncthreads();
        if (active) {
            int jj = 0;
            for (; jj + 4 <= m; jj += 4) {
                ushort4 v0 = *(const ushort4*)&gb[(size_t)s_j[jj]     * HF + cb];
                ushort4 v1 = *(const ushort4*)&gb[(size_t)s_j[jj + 1] * HF + cb];
                ushort4 v2 = *(const ushort4*)&gb[(size_t)s_j[jj + 2] * HF + cb];
                ushort4 v3 = *(const ushort4*)&gb[(size_t)s_j[jj + 3] * HF + cb];
                float w0 = s_w[jj * H + hh], w1 = s_w[(jj + 1) * H + hh];
                float w2 = s_w[(jj + 2) * H + hh], w3 = s_w[(jj + 3) * H + hh];
                a0 += w0 * bf2f(v0.x) + w1 * bf2f(v1.x) + w2 * bf2f(v2.x) + w3 * bf2f(v3.x);
                a1 += w0 * bf2f(v0.y) + w1 * bf2f(v1.y) + w2 * bf2f(v2.y) + w3 * bf2f(v3.y);
                a2 += w0 * bf2f(v0.z) + w1 * bf2f(v1.z) + w2 * bf2f(v2.z) + w3 * bf2f(v3.z);
                a3 += w0 * bf2f(v0.w) + w1 * bf2f(v1.w) + w2 * bf2f(v2.w) + w3 * bf2f(v3.w);
            }
            for (; jj < m; ++jj) {
                ushort4 v0 = *(const ushort4*)&gb[(size_t)s_j[jj] * HF + cb];
                float w0 = s_w[jj * H + hh];
                a0 += w0 * bf2f(v0.x); a1 += w0 * bf2f(v0.y);
                a2 += w0 * bf2f(v0.z); a3 += w0 * bf2f(v0.w);
            }
        }
    }

    if (active) {
        float vv[4] = {a0, a1, a2, a3};
        #pragma unroll
        for (int q = 0; q < 4; ++q) {
            float v = vv[q];
            if (mode == 0) v = (v > 0.f) ? v : expm1f(v);
            else           v += resid[(size_t)i * HF + cb + q];
            store_out(&dst[(size_t)i * dst_stride + dst_coloff + cb + q], v);
        }
    }
}

// ---------------------------------------------------------------------------
extern "C" void kernel_launch(void* const* d_in, const int* in_sizes, int n_in,
                              void* d_out, int out_size, void* d_ws, size_t ws_size,
                              hipStream_t stream)
{
    const float* feature = (const float*)d_in[0];
    const float* adj     = (const float*)d_in[1];
    const float* g1W1 = (const float*)d_in[2];
    const float* g1a1 = (const float*)d_in[3];
    const float* g1W2 = (const float*)d_in[4];
    const float* g1a2 = (const float*)d_in[5];
    const float* g2W1 = (const float*)d_in[6];
    const float* g2a1 = (const float*)d_in[7];
    const float* g2W2 = (const float*)d_in[8];
    const float* g2a2 = (const float*)d_in[9];
    const float* Wf  = (const float*)d_in[10];
    const float* bfv = (const float*)d_in[11];
    const float* fW1 = (const float*)d_in[12];
    const float* fb1 = (const float*)d_in[13];
    const float* fW2 = (const float*)d_in[14];
    const float* fb2 = (const float*)d_in[15];
    const float* fW3 = (const float*)d_in[16];
    const float* fb3 = (const float*)d_in[17];
    const float* oW1 = (const float*)d_in[18];
    const float* ob1 = (const float*)d_in[19];
    const float* oW2 = (const float*)d_in[20];
    const float* ob2 = (const float*)d_in[21];
    float* out = (float*)d_out;

    char* ws = (char*)d_ws;
    size_t off = 0;
    auto alloc = [&](size_t bytes) -> void* {
        void* p = ws + off;
        off = (off + bytes + 255) & ~(size_t)255;
        return p;
    };
    typedef unsigned short bf_t;
    int* sen_cnt = (int*)alloc((size_t)NN * 4);
    int* sec_cnt = (int*)alloc((size_t)NN * 4);
    unsigned short* sen_idx = (unsigned short*)alloc((size_t)NN * MAXDEG * 2);
    unsigned short* sec_idx = (unsigned short*)alloc((size_t)NN * 8 * 2);
    float* g1buf = (float*)alloc((size_t)NN * DHID * 4);
    bf_t*  g1b   = (bf_t*)alloc((size_t)NN * DHID * 2);
    float* gl1   = (float*)alloc((size_t)NN * NHEADS * 4);
    float* gr1   = (float*)alloc((size_t)NN * NHEADS * 4);
    bf_t*  x1    = (bf_t*)alloc((size_t)NN * DHID * 2);
    float* g2buf = (float*)alloc((size_t)NN * DIN * 4);
    bf_t*  g2b   = (bf_t*)alloc((size_t)NN * DIN * 2);
    float* gl2   = (float*)alloc((size_t)NN * 4);
    float* gr2   = (float*)alloc((size_t)NN * 4);
    float* gmean = (float*)alloc((size_t)DHID * 4);
    bf_t*  fcat  = (bf_t*)alloc((size_t)NN * (2 * DIN) * 2);
    bf_t*  fbuf  = (bf_t*)alloc((size_t)NN * DIN * 2);
    bf_t*  tA    = (bf_t*)alloc((size_t)NN * DFFN * 2);
    bf_t*  tB    = (bf_t*)alloc((size_t)NN * DFFN * 2);
    bf_t*  featb = (bf_t*)alloc((size_t)NN * DIN * 2);
    bf_t* g1W1T = (bf_t*)alloc((size_t)DIN * DHID * 2);
    bf_t* g1W2T = (bf_t*)alloc((size_t)DHID * DIN * 2);
    bf_t* g2W1T = (bf_t*)alloc((size_t)DIN * DHID * 2);
    bf_t* g2W2T = (bf_t*)alloc((size_t)DHID * DIN * 2);
    bf_t* WfT   = (bf_t*)alloc((size_t)(2 * DIN) * DIN * 2);
    bf_t* fW1T  = (bf_t*)alloc((size_t)DIN * DFFN * 2);
    bf_t* fW2T  = (bf_t*)alloc((size_t)DFFN * DFFN * 2);
    bf_t* fW3T  = (bf_t*)alloc((size_t)DFFN * DIN * 2);
    bf_t* oW1T  = (bf_t*)alloc((size_t)DIN * DFFN * 2);
    bf_t* oW2T  = (bf_t*)alloc((size_t)DFFN * DIN * 2);

    build_nbrs<<<NN, 256, 0, stream>>>(adj, sen_idx, sen_cnt, sec_idx, sec_cnt);
    auto tp = [&](const float* W, bf_t* WT, int K, int N) {
        transpose_cast<<<dim3(N / 32, K / 32), 256, 0, stream>>>(W, WT, K, N);
    };
    tp(g1W1, g1W1T, DIN, DHID);   tp(g1W2, g1W2T, DHID, DIN);
    tp(g2W1, g2W1T, DIN, DHID);   tp(g2W2, g2W2T, DHID, DIN);
    tp(Wf, WfT, 2 * DIN, DIN);
    tp(fW1, fW1T, DIN, DFFN);     tp(fW2, fW2T, DFFN, DFFN);
    tp(fW3, fW3T, DFFN, DIN);
    tp(oW1, oW1T, DIN, DFFN);     tp(oW2, oW2T, DFFN, DIN);
    cast_bf16<<<(NN * DIN) / 256, 256, 0, stream>>>(feature, featb, NN * DIN);

    auto run_gat = [&](const bf_t* W1T, const float* a1, const bf_t* W2T, const float* a2,
                       const unsigned short* idx, int idx_stride, const int* cnt, int coloff) {
        gemm_mfma<64, 64, float><<<dim3(DHID / 64, NN / 64), 256, 0, stream>>>(
            featb, W1T, nullptr, nullptr, g1buf, g1b, NN, DHID, DIN, 0);
        glgr_kernel<<<NN * NHEADS, 64, 0, stream>>>(g1buf, a1, FPRIME, gl1, gr1);
        zero_f32<<<DHID / 256, 256, 0, stream>>>(gmean, DHID);
        col_mean<<<dim3(DHID / 256, 16), 256, 0, stream>>>(g1buf, DHID, gmean);
        attn_agg<NHEADS, FPRIME, bf_t><<<NN, 256, 0, stream>>>(
            g1buf, g1b, gl1, gr1, idx, idx_stride, cnt, gmean, x1, DHID, 0, nullptr, 0);
        gemm_mfma<64, 64, float><<<dim3(DIN / 64, NN / 64), 256, 0, stream>>>(
            x1, W2T, nullptr, nullptr, g2buf, g2b, NN, DIN, DHID, 0);
        glgr_kernel<<<NN, 64, 0, stream>>>(g2buf, a2, DIN, gl2, gr2);
        zero_f32<<<DIN / 256, 256, 0, stream>>>(gmean, DIN);
        col_mean<<<dim3(DIN / 256, 16), 256, 0, stream>>>(g2buf, DIN, gmean);
        attn_agg<1, DIN, bf_t><<<NN, 256, 0, stream>>>(
            g2buf, g2b, gl2, gr2, idx, idx_stride, cnt, gmean, fcat, 2 * DIN, coloff, feature, 1);
    };

    run_gat(g1W1T, g1a1, g1W2T, g1a2, sen_idx, MAXDEG, sen_cnt, DIN);  // f_sen -> cols 768:1536
    run_gat(g2W1T, g2a1, g2W2T, g2a2, sec_idx, 8, sec_cnt, 0);         // f_sec -> cols 0:768

    gemm_mfma<64, 64, bf_t><<<dim3(DIN / 64, NN / 64), 256, 0, stream>>>(
        fcat, WfT, bfv, nullptr, fbuf, nullptr, NN, DIN, 2 * DIN, 1);
    gemm_mfma<64, 128, bf_t><<<dim3(DFFN / 128, NN / 64), 256, 0, stream>>>(
        fbuf, fW1T, fb1, nullptr, tA, nullptr, NN, DFFN, DIN, 1);
    gemm_mfma<64, 128, bf_t><<<dim3(DFFN / 128, NN / 64), 256, 0, stream>>>(
        tA, fW2T, fb2, nullptr, tB, nullptr, NN, DFFN, DFFN, 1);
    gemm_mfma<64, 64, bf_t><<<dim3(DIN / 64, NN / 64), 256, 0, stream>>>(
        tB, fW3T, fb3, nullptr, fbuf, nullptr, NN, DIN, DFFN, 1);
    gemm_mfma<64, 128, bf_t><<<dim3(DFFN / 128, NN / 64), 256, 0, stream>>>(
        fbuf, oW1T, ob1, nullptr, tA, nullptr, NN, DFFN, DIN, 1);
    gemm_mfma<64, 64, float><<<dim3(DIN / 64, NN / 64), 256, 0, stream>>>(
        tA, oW2T, ob2, feature, out, nullptr, NN, DIN, DFFN, 1);
}

// Round 6
// 447.292 us; speedup vs baseline: 3.1193x; 1.1675x over previous
//
#include <hip/hip_runtime.h>
#include <hip/hip_bf16.h>
#include <cmath>

#define NN 2048
#define DIN 768
#define DHID 1024
#define NHEADS 8
#define FPRIME 128
#define DFFN 2048
#define SEN_LIM 2042
#define MAXDEG 256

using short8 = __attribute__((ext_vector_type(8))) short;
using f32x4  = __attribute__((ext_vector_type(4))) float;

#if defined(__has_builtin)
#  if __has_builtin(__builtin_amdgcn_global_load_lds)
#    define HAVE_GLL 1
#  endif
#endif
#ifndef HAVE_GLL
#  define HAVE_GLL 0
#endif

__device__ inline unsigned short f2bf(float f) {
    unsigned u = __float_as_uint(f);
    unsigned r = u + 0x7FFFu + ((u >> 16) & 1u);   // RNE
    return (unsigned short)(r >> 16);
}
__device__ inline float bf2f(unsigned short h) {
    return __uint_as_float(((unsigned)h) << 16);
}
__device__ inline void store_out(float* p, float v) { *p = v; }
__device__ inline void store_out(unsigned short* p, float v) { *p = f2bf(v); }

#if HAVE_GLL
__device__ inline void gll16(const unsigned short* g, unsigned short* l) {
    __builtin_amdgcn_global_load_lds(
        (const __attribute__((address_space(1))) unsigned int*)g,
        (__attribute__((address_space(3))) unsigned int*)l, 16, 0, 0);
}
#endif

// ---------------------------------------------------------------------------
// Neighbor lists
// ---------------------------------------------------------------------------
__global__ __launch_bounds__(256) void build_nbrs(
    const float* __restrict__ adj,
    unsigned short* __restrict__ sen_idx, int* __restrict__ sen_cnt,
    unsigned short* __restrict__ sec_idx, int* __restrict__ sec_cnt)
{
    const int i = blockIdx.x;
    __shared__ int c_sen, c_sec;
    if (threadIdx.x == 0) { c_sen = 0; c_sec = 0; }
    __syncthreads();
    for (int j4 = threadIdx.x; j4 < NN / 4; j4 += 256) {
        float4 v = *(const float4*)&adj[(size_t)i * NN + j4 * 4];
        float vs[4] = {v.x, v.y, v.z, v.w};
        #pragma unroll
        for (int q = 0; q < 4; ++q) {
            if (vs[q] != 0.0f) {
                int j = j4 * 4 + q;
                if (j < SEN_LIM) {
                    int p = atomicAdd(&c_sen, 1);
                    if (p < MAXDEG) sen_idx[(size_t)i * MAXDEG + p] = (unsigned short)j;
                } else {
                    int p = atomicAdd(&c_sec, 1);
                    if (p < 8) sec_idx[i * 8 + p] = (unsigned short)j;
                }
            }
        }
    }
    __syncthreads();
    if (threadIdx.x == 0) { sen_cnt[i] = min(c_sen, MAXDEG); sec_cnt[i] = min(c_sec, 8); }
}

// ---------------------------------------------------------------------------
// Mega transpose/cast: all weight transposes (+feature cast) in one launch.
// trans=1: W[K][N] f32 -> d[N][K] bf16.  trans=0: straight cast [K][N].
// ---------------------------------------------------------------------------
struct TPJob { const float* s; unsigned short* d; int K, N, start, trans; };
struct TPJobs { TPJob j[11]; };

__global__ __launch_bounds__(256) void mega_tp(TPJobs jobs, int njobs)
{
    __shared__ float t[32][33];
    const int tile = blockIdx.x;
    int ji = 0;
    for (int k = 1; k < 11; ++k)
        if (k < njobs && tile >= jobs.j[k].start) ji = k;
    const TPJob jb = jobs.j[ji];
    const int lt = tile - jb.start;
    const int ntx = jb.N >> 5;
    const int bn = (lt % ntx) * 32, bk = (lt / ntx) * 32;
    const int tx = threadIdx.x & 31, ty = threadIdx.x >> 5;
    if (jb.trans) {
        #pragma unroll
        for (int r = 0; r < 4; ++r)
            t[ty + r * 8][tx] = jb.s[(size_t)(bk + ty + r * 8) * jb.N + bn + tx];
        __syncthreads();
        #pragma unroll
        for (int r = 0; r < 4; ++r) {
            int n = ty + r * 8;
            jb.d[(size_t)(bn + n) * jb.K + bk + tx] = f2bf(t[tx][n]);
        }
    } else {
        #pragma unroll
        for (int r = 0; r < 4; ++r) {
            size_t e = (size_t)(bk + ty + r * 8) * jb.N + bn + tx;
            jb.d[e] = f2bf(jb.s[e]);
        }
    }
}

// ---------------------------------------------------------------------------
// bf16 MFMA GEMM, XOR-swizzled LDS, optional dual problem via blockIdx.z.
// ---------------------------------------------------------------------------
template<int BM, int BN, typename OUT_T>
__global__ __launch_bounds__(256) void gemm_mfma(
    const unsigned short* __restrict__ A0, const unsigned short* __restrict__ A1,
    const unsigned short* __restrict__ BT0, const unsigned short* __restrict__ BT1,
    const float* __restrict__ bias, const float* __restrict__ resid,
    OUT_T* __restrict__ C0, OUT_T* __restrict__ C1,
    unsigned short* __restrict__ Cb0, unsigned short* __restrict__ Cb1,
    int M, int N, int K, int act)
{
    constexpr int BK = 64;
    constexpr int WR = BM / 64;
    constexpr int WC = 4 / WR;
    constexpr int NF = BN / (WC * 16);
    constexpr int ACH = BM / 32;
    constexpr int BCH = BN / 32;
    __shared__ unsigned short Asm[BM * BK];
    __shared__ unsigned short Bsm[BN * BK];
    const int z = blockIdx.z;
    const unsigned short* A  = z ? A1  : A0;
    const unsigned short* BT = z ? BT1 : BT0;
    OUT_T* C = z ? C1 : C0;
    unsigned short* Cb = z ? Cb1 : Cb0;
    const int tid = threadIdx.x;
    const int lane = tid & 63, w = tid >> 6;
    const int wr = w / WC, wc = w % WC;
    const int bm = blockIdx.y * BM, bn = blockIdx.x * BN;

    f32x4 acc[4][NF];
    #pragma unroll
    for (int mi = 0; mi < 4; ++mi)
        #pragma unroll
        for (int ni = 0; ni < NF; ++ni)
            acc[mi][ni] = (f32x4){0.f, 0.f, 0.f, 0.f};

    const unsigned short* Abase = A + (size_t)bm * K;
    const unsigned short* Bbase = BT + (size_t)bn * K;

    for (int k0 = 0; k0 < K; k0 += BK) {
        __syncthreads();
        #pragma unroll
        for (int c = 0; c < ACH; ++c) {
            int e = (tid + c * 256) * 8;
            int r = e >> 6, kk = e & 63;
            int kks = kk ^ ((r & 7) << 3);
#if HAVE_GLL
            gll16(&Abase[(size_t)r * K + k0 + kks], &Asm[e]);
#else
            *(short8*)&Asm[e] = *(const short8*)&Abase[(size_t)r * K + k0 + kks];
#endif
        }
        #pragma unroll
        for (int c = 0; c < BCH; ++c) {
            int e = (tid + c * 256) * 8;
            int r = e >> 6, kk = e & 63;
            int kks = kk ^ ((r & 7) << 3);
#if HAVE_GLL
            gll16(&Bbase[(size_t)r * K + k0 + kks], &Bsm[e]);
#else
            *(short8*)&Bsm[e] = *(const short8*)&Bbase[(size_t)r * K + k0 + kks];
#endif
        }
        __syncthreads();
        #pragma unroll
        for (int ks = 0; ks < 2; ++ks) {
            short8 af[4], bfv[NF];
            #pragma unroll
            for (int mi = 0; mi < 4; ++mi) {
                int row = wr * 64 + mi * 16 + (lane & 15);
                int col = (ks * 32 + (lane >> 4) * 8) ^ ((row & 7) << 3);
                af[mi] = *(const short8*)&Asm[row * 64 + col];
            }
            #pragma unroll
            for (int ni = 0; ni < NF; ++ni) {
                int row = wc * (BN / WC) + ni * 16 + (lane & 15);
                int col = (ks * 32 + (lane >> 4) * 8) ^ ((row & 7) << 3);
                bfv[ni] = *(const short8*)&Bsm[row * 64 + col];
            }
            #pragma unroll
            for (int mi = 0; mi < 4; ++mi)
                #pragma unroll
                for (int ni = 0; ni < NF; ++ni)
                    acc[mi][ni] = __builtin_amdgcn_mfma_f32_16x16x32_bf16(
                        af[mi], bfv[ni], acc[mi][ni], 0, 0, 0);
        }
    }

    const int rbase = bm + wr * 64;
    const int cbase = bn + wc * (BN / WC);
    #pragma unroll
    for (int mi = 0; mi < 4; ++mi)
        #pragma unroll
        for (int ni = 0; ni < NF; ++ni)
            #pragma unroll
            for (int r = 0; r < 4; ++r) {
                int grow = rbase + mi * 16 + (lane >> 4) * 4 + r;
                int gcol = cbase + ni * 16 + (lane & 15);
                float v = acc[mi][ni][r];
                if (bias)  v += bias[gcol];
                if (act)   v = (v >= 0.f) ? v : 0.01f * v;
                if (resid) v += resid[(size_t)grow * N + gcol];
                store_out(&C[(size_t)grow * N + gcol], v);
                if (Cb) Cb[(size_t)grow * N + gcol] = f2bf(v);
            }
}

// ---------------------------------------------------------------------------
// Fused gl/gr for both branches (bf16 g input) + gmean zeroing.
// grid = 2 * nb_per_branch blocks of 64.
// ---------------------------------------------------------------------------
__global__ __launch_bounds__(64) void glgr2(
    const unsigned short* __restrict__ gA, const unsigned short* __restrict__ gB,
    int row_stride, int F, int Hlog2, int nb_per_branch,
    const float* __restrict__ aA, const float* __restrict__ aB,
    float* __restrict__ glA, float* __restrict__ grA,
    float* __restrict__ glB, float* __restrict__ grB,
    float* __restrict__ z, int zblocks)
{
    const int bid = blockIdx.x, lane = threadIdx.x;
    if (bid < zblocks) z[bid * 64 + lane] = 0.f;
    const int br = bid >= nb_per_branch;
    const int b = br ? bid - nb_per_branch : bid;
    const int node = b >> Hlog2, h = b - ((b >> Hlog2) << Hlog2);
    const unsigned short* g = (br ? gB : gA) + (size_t)node * row_stride + h * F;
    const float* a = br ? aB : aA;
    float sl = 0.f, sr = 0.f;
    for (int f = lane; f < F; f += 64) {
        float v = bf2f(g[f]);
        sl += v * a[f];
        sr += v * a[F + f];
    }
    #pragma unroll
    for (int off = 32; off > 0; off >>= 1) {
        sl += __shfl_down(sl, off);
        sr += __shfl_down(sr, off);
    }
    if (lane == 0) {
        (br ? glB : glA)[b] = sl;
        (br ? grB : grA)[b] = sr;
    }
}

// col-mean of bf16 matrix; z selects problem. out pre-zeroed (by glgr2).
__global__ __launch_bounds__(256) void col_mean2(
    const unsigned short* __restrict__ g0, const unsigned short* __restrict__ g1,
    int C, float* __restrict__ o0, float* __restrict__ o1)
{
    const unsigned short* g = blockIdx.z ? g1 : g0;
    float* o = blockIdx.z ? o1 : o0;
    int c = blockIdx.x * 256 + threadIdx.x;
    int r0 = blockIdx.y * 128;
    float s = 0.f;
    for (int r = r0; r < r0 + 128; ++r) s += bf2f(g[(size_t)r * C + c]);
    atomicAdd(&o[c], s * (1.0f / 2048.0f));
}

// ---------------------------------------------------------------------------
// Fused sparse GAT attention+aggregation, both branches (grid = 2*NN).
// Gather unrolled x8. mode 0: ELU; mode 1: += resid.
// ---------------------------------------------------------------------------
template<int H, int F, typename OUT_T>
__global__ __launch_bounds__(256) void attn_agg2(
    const unsigned short* __restrict__ gb0, const unsigned short* __restrict__ gb1,
    int g_stride,
    const float* __restrict__ gl0, const float* __restrict__ gr0,
    const float* __restrict__ gl1, const float* __restrict__ gr1,
    const unsigned short* __restrict__ idx0, int is0, const int* __restrict__ cnt0,
    const unsigned short* __restrict__ idx1, int is1, const int* __restrict__ cnt1,
    const float* __restrict__ gmean0, const float* __restrict__ gmean1,
    OUT_T* __restrict__ dst0, OUT_T* __restrict__ dst1,
    int dst_stride, int co0, int co1,
    const float* __restrict__ resid, int mode)
{
    constexpr int HF = H * F;
    const int bid = blockIdx.x;
    const int br = bid >= NN;
    const int i = br ? bid - NN : bid;
    const unsigned short* gbp = br ? gb1 : gb0;
    const float* gl = br ? gl1 : gl0;
    const float* gr = br ? gr1 : gr0;
    const unsigned short* idx = br ? idx1 : idx0;
    const int is = br ? is1 : is0;
    const int* cnt = br ? cnt1 : cnt0;
    const float* gmean = br ? gmean1 : gmean0;
    OUT_T* dst = br ? dst1 : dst0;
    const int co = br ? co1 : co0;

    const int tid = threadIdx.x;
    const int lane = tid & 63, w = tid >> 6;
    const int n = cnt[i];

    if (n == 0) {
        for (int c = tid; c < HF; c += 256) {
            float v = gmean[c];
            if (mode == 0) v = (v > 0.f) ? v : expm1f(v);
            else           v += resid[(size_t)i * HF + c];
            store_out(&dst[(size_t)i * dst_stride + co + c], v);
        }
        return;
    }

    __shared__ float s_wred[4 * H];
    __shared__ float s_max[H], s_inv[H], s_glh[H];
    __shared__ float s_w[128 * H];
    __shared__ unsigned short s_j[128];

    if (tid < H) s_glh[tid] = gl[(size_t)i * H + tid];
    __syncthreads();
    float glh[H];
    #pragma unroll
    for (int h = 0; h < H; ++h) glh[h] = s_glh[h];

    const unsigned short* row_idx = idx + (size_t)i * is;

    // Pass 1: per-head max
    float pmax[H];
    #pragma unroll
    for (int h = 0; h < H; ++h) pmax[h] = -1e30f;
    for (int jj = tid; jj < n; jj += 256) {
        int j = row_idx[jj];
        if (H == 8) {
            float4 ga = *(const float4*)&gr[(size_t)j * 8];
            float4 gbv = *(const float4*)&gr[(size_t)j * 8 + 4];
            float sc[8] = {ga.x, ga.y, ga.z, ga.w, gbv.x, gbv.y, gbv.z, gbv.w};
            #pragma unroll
            for (int h = 0; h < H; ++h) {
                float s = glh[h] + sc[h];
                s = (s >= 0.f) ? s : 0.2f * s;
                pmax[h] = fmaxf(pmax[h], s);
            }
        } else {
            float s = glh[0] + gr[j];
            s = (s >= 0.f) ? s : 0.2f * s;
            pmax[0] = fmaxf(pmax[0], s);
        }
    }
    #pragma unroll
    for (int h = 0; h < H; ++h)
        #pragma unroll
        for (int off = 32; off > 0; off >>= 1)
            pmax[h] = fmaxf(pmax[h], __shfl_xor(pmax[h], off));
    if (lane == 0)
        #pragma unroll
        for (int h = 0; h < H; ++h) s_wred[w * H + h] = pmax[h];
    __syncthreads();
    if (tid < H)
        s_max[tid] = fmaxf(fmaxf(s_wred[tid], s_wred[H + tid]),
                           fmaxf(s_wred[2 * H + tid], s_wred[3 * H + tid]));
    __syncthreads();
    float mx[H];
    #pragma unroll
    for (int h = 0; h < H; ++h) mx[h] = s_max[h];

    // Pass 2: per-head exp-sum
    float psum[H];
    #pragma unroll
    for (int h = 0; h < H; ++h) psum[h] = 0.f;
    for (int jj = tid; jj < n; jj += 256) {
        int j = row_idx[jj];
        if (H == 8) {
            float4 ga = *(const float4*)&gr[(size_t)j * 8];
            float4 gbv = *(const float4*)&gr[(size_t)j * 8 + 4];
            float sc[8] = {ga.x, ga.y, ga.z, ga.w, gbv.x, gbv.y, gbv.z, gbv.w};
            #pragma unroll
            for (int h = 0; h < H; ++h) {
                float s = glh[h] + sc[h];
                s = (s >= 0.f) ? s : 0.2f * s;
                psum[h] += expf(s - mx[h]);
            }
        } else {
            float s = glh[0] + gr[j];
            s = (s >= 0.f) ? s : 0.2f * s;
            psum[0] += expf(s - mx[0]);
        }
    }
    #pragma unroll
    for (int h = 0; h < H; ++h)
        #pragma unroll
        for (int off = 32; off > 0; off >>= 1)
            psum[h] += __shfl_xor(psum[h], off);
    if (lane == 0)
        #pragma unroll
        for (int h = 0; h < H; ++h) s_wred[w * H + h] = psum[h];
    __syncthreads();
    if (tid < H)
        s_inv[tid] = 1.f / (s_wred[tid] + s_wred[H + tid] +
                            s_wred[2 * H + tid] + s_wred[3 * H + tid]);
    // ordering barrier supplied by first pass-3 iteration

    // Pass 3: bf16 gather, 4 consecutive cols/thread, unrolled x8
    const int cb = tid * 4;
    const bool active = (cb < HF);
    const int hh = (H == 8) ? (cb >> 7) : 0;
    float a0 = 0.f, a1 = 0.f, a2 = 0.f, a3 = 0.f;

    for (int c0 = 0; c0 < n; c0 += 128) {
        int m = min(128, n - c0);
        __syncthreads();
        for (int e = tid; e < m * H; e += 256) {
            int jj = (H == 8) ? (e >> 3) : e;
            int h  = (H == 8) ? (e & 7) : 0;
            int j = row_idx[c0 + jj];
            float s = glh[h] + gr[(size_t)j * H + h];
            s = (s >= 0.f) ? s : 0.2f * s;
            s_w[jj * H + h] = expf(s - s_max[h]) * s_inv[h];
            if (h == 0) s_j[jj] = (unsigned short)j;
        }
        __syncthreads();
        if (active) {
            int jj = 0;
            for (; jj + 8 <= m; jj += 8) {
                ushort4 v[8]; float wv[8];
                #pragma unroll
                for (int u = 0; u < 8; ++u) {
                    v[u] = *(const ushort4*)&gbp[(size_t)s_j[jj + u] * g_stride + cb];
                    wv[u] = s_w[(jj + u) * H + hh];
                }
                #pragma unroll
                for (int u = 0; u < 8; ++u) {
                    a0 += wv[u] * bf2f(v[u].x);
                    a1 += wv[u] * bf2f(v[u].y);
                    a2 += wv[u] * bf2f(v[u].z);
                    a3 += wv[u] * bf2f(v[u].w);
                }
            }
            for (; jj < m; ++jj) {
                ushort4 v0 = *(const ushort4*)&gbp[(size_t)s_j[jj] * g_stride + cb];
                float w0 = s_w[jj * H + hh];
                a0 += w0 * bf2f(v0.x); a1 += w0 * bf2f(v0.y);
                a2 += w0 * bf2f(v0.z); a3 += w0 * bf2f(v0.w);
            }
        }
    }

    if (active) {
        float vv[4] = {a0, a1, a2, a3};
        #pragma unroll
        for (int q = 0; q < 4; ++q) {
            float v = vv[q];
            if (mode == 0) v = (v > 0.f) ? v : expm1f(v);
            else           v += resid[(size_t)i * HF + cb + q];
            store_out(&dst[(size_t)i * dst_stride + co + cb + q], v);
        }
    }
}

// ---------------------------------------------------------------------------
extern "C" void kernel_launch(void* const* d_in, const int* in_sizes, int n_in,
                              void* d_out, int out_size, void* d_ws, size_t ws_size,
                              hipStream_t stream)
{
    const float* feature = (const float*)d_in[0];
    const float* adj     = (const float*)d_in[1];
    const float* g1W1 = (const float*)d_in[2];
    const float* g1a1 = (const float*)d_in[3];
    const float* g1W2 = (const float*)d_in[4];
    const float* g1a2 = (const float*)d_in[5];
    const float* g2W1 = (const float*)d_in[6];
    const float* g2a1 = (const float*)d_in[7];
    const float* g2W2 = (const float*)d_in[8];
    const float* g2a2 = (const float*)d_in[9];
    const float* Wf  = (const float*)d_in[10];
    const float* bfv = (const float*)d_in[11];
    const float* fW1 = (const float*)d_in[12];
    const float* fb1 = (const float*)d_in[13];
    const float* fW2 = (const float*)d_in[14];
    const float* fb2 = (const float*)d_in[15];
    const float* fW3 = (const float*)d_in[16];
    const float* fb3 = (const float*)d_in[17];
    const float* oW1 = (const float*)d_in[18];
    const float* ob1 = (const float*)d_in[19];
    const float* oW2 = (const float*)d_in[20];
    const float* ob2 = (const float*)d_in[21];
    float* out = (float*)d_out;

    char* ws = (char*)d_ws;
    size_t off = 0;
    auto alloc = [&](size_t bytes) -> void* {
        void* p = ws + off;
        off = (off + bytes + 255) & ~(size_t)255;
        return p;
    };
    typedef unsigned short bf_t;
    int* sen_cnt = (int*)alloc((size_t)NN * 4);
    int* sec_cnt = (int*)alloc((size_t)NN * 4);
    unsigned short* sen_idx = (unsigned short*)alloc((size_t)NN * MAXDEG * 2);
    unsigned short* sec_idx = (unsigned short*)alloc((size_t)NN * 8 * 2);
    bf_t*  g1b   = (bf_t*)alloc((size_t)NN * 2048 * 2);       // fused layer-1 g (both branches)
    float* gl1a  = (float*)alloc((size_t)NN * NHEADS * 4);
    float* gr1a  = (float*)alloc((size_t)NN * NHEADS * 4);
    float* gl1b  = (float*)alloc((size_t)NN * NHEADS * 4);
    float* gr1b  = (float*)alloc((size_t)NN * NHEADS * 4);
    bf_t*  x1a   = (bf_t*)alloc((size_t)NN * DHID * 2);
    bf_t*  x1b   = (bf_t*)alloc((size_t)NN * DHID * 2);
    bf_t*  g2aB  = (bf_t*)alloc((size_t)NN * DIN * 2);
    bf_t*  g2bB  = (bf_t*)alloc((size_t)NN * DIN * 2);
    float* gl2a  = (float*)alloc((size_t)NN * 4);
    float* gr2a  = (float*)alloc((size_t)NN * 4);
    float* gl2b  = (float*)alloc((size_t)NN * 4);
    float* gr2b  = (float*)alloc((size_t)NN * 4);
    float* gmeanL1 = (float*)alloc((size_t)2048 * 4);         // fused (branch0 cols 0..1023)
    float* gmeanL2 = (float*)alloc((size_t)1536 * 4);         // [0..768) a, [768..1536) b
    bf_t*  fcat  = (bf_t*)alloc((size_t)NN * (2 * DIN) * 2);
    bf_t*  fbuf  = (bf_t*)alloc((size_t)NN * DIN * 2);
    bf_t*  tA    = (bf_t*)alloc((size_t)NN * DFFN * 2);
    bf_t*  tB    = (bf_t*)alloc((size_t)NN * DFFN * 2);
    bf_t*  featb = (bf_t*)alloc((size_t)NN * DIN * 2);
    bf_t* W1T_AB = (bf_t*)alloc((size_t)2048 * DIN * 2);      // [g1W1T ; g2W1T]
    bf_t* g1W2T = (bf_t*)alloc((size_t)DHID * DIN * 2);
    bf_t* g2W2T = (bf_t*)alloc((size_t)DHID * DIN * 2);
    bf_t* WfT   = (bf_t*)alloc((size_t)(2 * DIN) * DIN * 2);
    bf_t* fW1T  = (bf_t*)alloc((size_t)DIN * DFFN * 2);
    bf_t* fW2T  = (bf_t*)alloc((size_t)DFFN * DFFN * 2);
    bf_t* fW3T  = (bf_t*)alloc((size_t)DFFN * DIN * 2);
    bf_t* oW1T  = (bf_t*)alloc((size_t)DIN * DFFN * 2);
    bf_t* oW2T  = (bf_t*)alloc((size_t)DFFN * DIN * 2);

    build_nbrs<<<NN, 256, 0, stream>>>(adj, sen_idx, sen_cnt, sec_idx, sec_cnt);

    // All transposes + feature cast in one launch.
    TPJobs jobs;
    int cur = 0, nj = 0;
    auto addjob = [&](const float* s, bf_t* d, int K, int N, int trans) {
        jobs.j[nj] = {s, d, K, N, cur, trans};
        cur += (K / 32) * (N / 32);
        ++nj;
    };
    addjob(g1W1, W1T_AB, DIN, DHID, 1);                 // rows 0..1023
    addjob(g2W1, W1T_AB + (size_t)1024 * DIN, DIN, DHID, 1);
    addjob(g1W2, g1W2T, DHID, DIN, 1);
    addjob(g2W2, g2W2T, DHID, DIN, 1);
    addjob(Wf, WfT, 2 * DIN, DIN, 1);
    addjob(fW1, fW1T, DIN, DFFN, 1);
    addjob(fW2, fW2T, DFFN, DFFN, 1);
    addjob(fW3, fW3T, DFFN, DIN, 1);
    addjob(oW1, oW1T, DIN, DFFN, 1);
    addjob(oW2, oW2T, DFFN, DIN, 1);
    addjob(feature, featb, NN, DIN, 0);
    mega_tp<<<cur, 256, 0, stream>>>(jobs, nj);

    // Layer-1 GEMM, both branches fused: [2048,768] @ [768,2048] -> g1b bf16
    gemm_mfma<64, 128, bf_t><<<dim3(2048 / 128, NN / 64, 1), 256, 0, stream>>>(
        featb, nullptr, W1T_AB, nullptr, nullptr, nullptr,
        g1b, nullptr, nullptr, nullptr, NN, 2048, DIN, 0);

    // gl/gr both branches + zero gmeanL1 (2048 floats = 32 blocks)
    glgr2<<<2 * NN * NHEADS, 64, 0, stream>>>(
        g1b, g1b + 1024, 2048, FPRIME, 3, NN * NHEADS,
        g1a1, g2a1, gl1a, gr1a, gl1b, gr1b, gmeanL1, 32);
    col_mean2<<<dim3(2048 / 256, 16, 1), 256, 0, stream>>>(
        g1b, nullptr, 2048, gmeanL1, nullptr);
    attn_agg2<NHEADS, FPRIME, bf_t><<<2 * NN, 256, 0, stream>>>(
        g1b, g1b + 1024, 2048,
        gl1a, gr1a, gl1b, gr1b,
        sen_idx, MAXDEG, sen_cnt, sec_idx, 8, sec_cnt,
        gmeanL1, gmeanL1 + 1024,
        x1a, x1b, DHID, 0, 0, nullptr, 0);

    // Layer-2 dual GEMM: x1{a,b} @ W2{a,b}^T -> g2{a,b} bf16
    gemm_mfma<64, 64, bf_t><<<dim3(DIN / 64, NN / 64, 2), 256, 0, stream>>>(
        x1a, x1b, g1W2T, g2W2T, nullptr, nullptr,
        g2aB, g2bB, nullptr, nullptr, NN, DIN, DHID, 0);

    glgr2<<<2 * NN, 64, 0, stream>>>(
        g2aB, g2bB, DIN, DIN, 0, NN,
        g1a2, g2a2, gl2a, gr2a, gl2b, gr2b, gmeanL2, 24);
    col_mean2<<<dim3(DIN / 256, 16, 2), 256, 0, stream>>>(
        g2aB, g2bB, DIN, gmeanL2, gmeanL2 + DIN);
    // branch0 = gat1 = sen -> fcat cols 768..1535; branch1 = gat2 = sec -> 0..767
    attn_agg2<1, DIN, bf_t><<<2 * NN, 256, 0, stream>>>(
        g2aB, g2bB, DIN,
        gl2a, gr2a, gl2b, gr2b,
        sen_idx, MAXDEG, sen_cnt, sec_idx, 8, sec_cnt,
        gmeanL2, gmeanL2 + DIN,
        fcat, fcat, 2 * DIN, DIN, 0, feature, 1);

    // Fusion + MLP chain
    gemm_mfma<64, 64, bf_t><<<dim3(DIN / 64, NN / 64, 1), 256, 0, stream>>>(
        fcat, nullptr, WfT, nullptr, bfv, nullptr,
        fbuf, nullptr, nullptr, nullptr, NN, DIN, 2 * DIN, 1);
    gemm_mfma<64, 128, bf_t><<<dim3(DFFN / 128, NN / 64, 1), 256, 0, stream>>>(
        fbuf, nullptr, fW1T, nullptr, fb1, nullptr,
        tA, nullptr, nullptr, nullptr, NN, DFFN, DIN, 1);
    gemm_mfma<64, 128, bf_t><<<dim3(DFFN / 128, NN / 64, 1), 256, 0, stream>>>(
        tA, nullptr, fW2T, nullptr, fb2, nullptr,
        tB, nullptr, nullptr, nullptr, NN, DFFN, DFFN, 1);
    gemm_mfma<64, 64, bf_t><<<dim3(DIN / 64, NN / 64, 1), 256, 0, stream>>>(
        tB, nullptr, fW3T, nullptr, fb3, nullptr,
        fbuf, nullptr, nullptr, nullptr, NN, DIN, DFFN, 1);
    gemm_mfma<64, 128, bf_t><<<dim3(DFFN / 128, NN / 64, 1), 256, 0, stream>>>(
        fbuf, nullptr, oW1T, nullptr, ob1, nullptr,
        tA, nullptr, nullptr, nullptr, NN, DFFN, DIN, 1);
    gemm_mfma<64, 64, float><<<dim3(DIN / 64, NN / 64, 1), 256, 0, stream>>>(
        tA, nullptr, oW2T, nullptr, ob2, feature,
        out, nullptr, nullptr, nullptr, NN, DIN, DFFN, 1);
}

// Round 7
// 441.570 us; speedup vs baseline: 3.1598x; 1.0130x over previous
//
#include <hip/hip_runtime.h>
#include <hip/hip_bf16.h>
#include <cmath>

#define NN 2048
#define DIN 768
#define DHID 1024
#define NHEADS 8
#define FPRIME 128
#define DFFN 2048
#define SEN_LIM 2042
#define MAXDEG 256

using short8 = __attribute__((ext_vector_type(8))) short;
using f32x4  = __attribute__((ext_vector_type(4))) float;

#if defined(__has_builtin)
#  if __has_builtin(__builtin_amdgcn_global_load_lds)
#    define HAVE_GLL 1
#  endif
#endif
#ifndef HAVE_GLL
#  define HAVE_GLL 0
#endif

__device__ inline unsigned short f2bf(float f) {
    unsigned u = __float_as_uint(f);
    unsigned r = u + 0x7FFFu + ((u >> 16) & 1u);   // RNE
    return (unsigned short)(r >> 16);
}
__device__ inline float bf2f(unsigned short h) {
    return __uint_as_float(((unsigned)h) << 16);
}
__device__ inline void store_out(float* p, float v) { *p = v; }
__device__ inline void store_out(unsigned short* p, float v) { *p = f2bf(v); }

#if HAVE_GLL
__device__ inline void gll16(const unsigned short* g, unsigned short* l) {
    __builtin_amdgcn_global_load_lds(
        (const __attribute__((address_space(1))) unsigned int*)g,
        (__attribute__((address_space(3))) unsigned int*)l, 16, 0, 0);
}
#endif

template<int S> __device__ inline void wait_vmcnt() {
    if constexpr (S == 0)      asm volatile("s_waitcnt vmcnt(0)" ::: "memory");
    else if constexpr (S == 4) asm volatile("s_waitcnt vmcnt(4)" ::: "memory");
    else if constexpr (S == 6) asm volatile("s_waitcnt vmcnt(6)" ::: "memory");
    else                       asm volatile("s_waitcnt vmcnt(8)" ::: "memory");
}

// ---------------------------------------------------------------------------
// Neighbor lists
// ---------------------------------------------------------------------------
__global__ __launch_bounds__(256) void build_nbrs(
    const float* __restrict__ adj,
    unsigned short* __restrict__ sen_idx, int* __restrict__ sen_cnt,
    unsigned short* __restrict__ sec_idx, int* __restrict__ sec_cnt)
{
    const int i = blockIdx.x;
    __shared__ int c_sen, c_sec;
    if (threadIdx.x == 0) { c_sen = 0; c_sec = 0; }
    __syncthreads();
    for (int j4 = threadIdx.x; j4 < NN / 4; j4 += 256) {
        float4 v = *(const float4*)&adj[(size_t)i * NN + j4 * 4];
        float vs[4] = {v.x, v.y, v.z, v.w};
        #pragma unroll
        for (int q = 0; q < 4; ++q) {
            if (vs[q] != 0.0f) {
                int j = j4 * 4 + q;
                if (j < SEN_LIM) {
                    int p = atomicAdd(&c_sen, 1);
                    if (p < MAXDEG) sen_idx[(size_t)i * MAXDEG + p] = (unsigned short)j;
                } else {
                    int p = atomicAdd(&c_sec, 1);
                    if (p < 8) sec_idx[i * 8 + p] = (unsigned short)j;
                }
            }
        }
    }
    __syncthreads();
    if (threadIdx.x == 0) { sen_cnt[i] = min(c_sen, MAXDEG); sec_cnt[i] = min(c_sec, 8); }
}

// ---------------------------------------------------------------------------
// Mega transpose/cast
// ---------------------------------------------------------------------------
struct TPJob { const float* s; unsigned short* d; int K, N, start, trans; };
struct TPJobs { TPJob j[11]; };

__global__ __launch_bounds__(256) void mega_tp(TPJobs jobs, int njobs)
{
    __shared__ float t[32][33];
    const int tile = blockIdx.x;
    int ji = 0;
    for (int k = 1; k < 11; ++k)
        if (k < njobs && tile >= jobs.j[k].start) ji = k;
    const TPJob jb = jobs.j[ji];
    const int lt = tile - jb.start;
    const int ntx = jb.N >> 5;
    const int bn = (lt % ntx) * 32, bk = (lt / ntx) * 32;
    const int tx = threadIdx.x & 31, ty = threadIdx.x >> 5;
    if (jb.trans) {
        #pragma unroll
        for (int r = 0; r < 4; ++r)
            t[ty + r * 8][tx] = jb.s[(size_t)(bk + ty + r * 8) * jb.N + bn + tx];
        __syncthreads();
        #pragma unroll
        for (int r = 0; r < 4; ++r) {
            int n = ty + r * 8;
            jb.d[(size_t)(bn + n) * jb.K + bk + tx] = f2bf(t[tx][n]);
        }
    } else {
        #pragma unroll
        for (int r = 0; r < 4; ++r) {
            size_t e = (size_t)(bk + ty + r * 8) * jb.N + bn + tx;
            jb.d[e] = f2bf(jb.s[e]);
        }
    }
}

// ---------------------------------------------------------------------------
// bf16 MFMA GEMM: XOR-swizzled LDS + double-buffered 2-phase pipeline
// (T3 minimum: prefetch next K-tile via global_load_lds, raw s_barrier +
// counted vmcnt so prefetch stays in flight across barriers).
// Optional dual problem via blockIdx.z.
// ---------------------------------------------------------------------------
template<int BM, int BN, typename OUT_T>
__global__ __launch_bounds__(256) void gemm_mfma(
    const unsigned short* __restrict__ A0, const unsigned short* __restrict__ A1,
    const unsigned short* __restrict__ BT0, const unsigned short* __restrict__ BT1,
    const float* __restrict__ bias, const float* __restrict__ resid,
    OUT_T* __restrict__ C0, OUT_T* __restrict__ C1,
    unsigned short* __restrict__ Cb0, unsigned short* __restrict__ Cb1,
    int M, int N, int K, int act)
{
    constexpr int BK = 64;
    constexpr int WR = BM / 64;
    constexpr int WC = 4 / WR;
    constexpr int NF = BN / (WC * 16);
    constexpr int ACH = BM / 32;
    constexpr int BCH = BN / 32;
    constexpr int S = ACH + BCH;         // gll ops per thread per tile
    __shared__ unsigned short Asm[2][BM * BK];
    __shared__ unsigned short Bsm[2][BN * BK];
    const int z = blockIdx.z;
    const unsigned short* A  = z ? A1  : A0;
    const unsigned short* BT = z ? BT1 : BT0;
    OUT_T* C = z ? C1 : C0;
    unsigned short* Cb = z ? Cb1 : Cb0;
    const int tid = threadIdx.x;
    const int lane = tid & 63, w = tid >> 6;
    const int wr = w / WC, wc = w % WC;
    const int bm = blockIdx.y * BM, bn = blockIdx.x * BN;

    f32x4 acc[4][NF];
    #pragma unroll
    for (int mi = 0; mi < 4; ++mi)
        #pragma unroll
        for (int ni = 0; ni < NF; ++ni)
            acc[mi][ni] = (f32x4){0.f, 0.f, 0.f, 0.f};

    const unsigned short* Abase = A + (size_t)bm * K;
    const unsigned short* Bbase = BT + (size_t)bn * K;

    auto stage = [&](int b, int k0) {
        #pragma unroll
        for (int c = 0; c < ACH; ++c) {
            int e = (tid + c * 256) * 8;
            int r = e >> 6, kk = e & 63;
            int kks = kk ^ ((r & 7) << 3);   // pre-swizzled source col
#if HAVE_GLL
            gll16(&Abase[(size_t)r * K + k0 + kks], &Asm[b][e]);
#else
            *(short8*)&Asm[b][e] = *(const short8*)&Abase[(size_t)r * K + k0 + kks];
#endif
        }
        #pragma unroll
        for (int c = 0; c < BCH; ++c) {
            int e = (tid + c * 256) * 8;
            int r = e >> 6, kk = e & 63;
            int kks = kk ^ ((r & 7) << 3);
#if HAVE_GLL
            gll16(&Bbase[(size_t)r * K + k0 + kks], &Bsm[b][e]);
#else
            *(short8*)&Bsm[b][e] = *(const short8*)&Bbase[(size_t)r * K + k0 + kks];
#endif
        }
    };

    const int nk = K / BK;
    stage(0, 0);                         // prologue prefetch
    int buf = 0;
    for (int t = 0; t < nk; ++t) {
        if (t + 1 < nk) {
            stage(buf ^ 1, (t + 1) * BK); // issue next tile (stays in flight)
            wait_vmcnt<S>();              // oldest S (= current tile) landed
        } else {
            wait_vmcnt<0>();
        }
        __builtin_amdgcn_s_barrier();    // all waves: current tile ready
        #pragma unroll
        for (int ks = 0; ks < 2; ++ks) {
            short8 af[4], bfv[NF];
            #pragma unroll
            for (int mi = 0; mi < 4; ++mi) {
                int row = wr * 64 + mi * 16 + (lane & 15);
                int col = (ks * 32 + (lane >> 4) * 8) ^ ((row & 7) << 3);
                af[mi] = *(const short8*)&Asm[buf][row * 64 + col];
            }
            #pragma unroll
            for (int ni = 0; ni < NF; ++ni) {
                int row = wc * (BN / WC) + ni * 16 + (lane & 15);
                int col = (ks * 32 + (lane >> 4) * 8) ^ ((row & 7) << 3);
                bfv[ni] = *(const short8*)&Bsm[buf][row * 64 + col];
            }
            #pragma unroll
            for (int mi = 0; mi < 4; ++mi)
                #pragma unroll
                for (int ni = 0; ni < NF; ++ni)
                    acc[mi][ni] = __builtin_amdgcn_mfma_f32_16x16x32_bf16(
                        af[mi], bfv[ni], acc[mi][ni], 0, 0, 0);
        }
        __builtin_amdgcn_s_barrier();    // all reads of buf done before restage
        buf ^= 1;
    }

    const int rbase = bm + wr * 64;
    const int cbase = bn + wc * (BN / WC);
    #pragma unroll
    for (int mi = 0; mi < 4; ++mi)
        #pragma unroll
        for (int ni = 0; ni < NF; ++ni)
            #pragma unroll
            for (int r = 0; r < 4; ++r) {
                int grow = rbase + mi * 16 + (lane >> 4) * 4 + r;
                int gcol = cbase + ni * 16 + (lane & 15);
                float v = acc[mi][ni][r];
                if (bias)  v += bias[gcol];
                if (act)   v = (v >= 0.f) ? v : 0.01f * v;
                if (resid) v += resid[(size_t)grow * N + gcol];
                store_out(&C[(size_t)grow * N + gcol], v);
                if (Cb) Cb[(size_t)grow * N + gcol] = f2bf(v);
            }
}

// ---------------------------------------------------------------------------
// Fused gl/gr for both branches (bf16 g input) + gmean zeroing.
// ---------------------------------------------------------------------------
__global__ __launch_bounds__(64) void glgr2(
    const unsigned short* __restrict__ gA, const unsigned short* __restrict__ gB,
    int row_stride, int F, int Hlog2, int nb_per_branch,
    const float* __restrict__ aA, const float* __restrict__ aB,
    float* __restrict__ glA, float* __restrict__ grA,
    float* __restrict__ glB, float* __restrict__ grB,
    float* __restrict__ z, int zblocks)
{
    const int bid = blockIdx.x, lane = threadIdx.x;
    if (bid < zblocks) z[bid * 64 + lane] = 0.f;
    const int br = bid >= nb_per_branch;
    const int b = br ? bid - nb_per_branch : bid;
    const int node = b >> Hlog2, h = b - ((b >> Hlog2) << Hlog2);
    const unsigned short* g = (br ? gB : gA) + (size_t)node * row_stride + h * F;
    const float* a = br ? aB : aA;
    float sl = 0.f, sr = 0.f;
    for (int f = lane; f < F; f += 64) {
        float v = bf2f(g[f]);
        sl += v * a[f];
        sr += v * a[F + f];
    }
    #pragma unroll
    for (int off = 32; off > 0; off >>= 1) {
        sl += __shfl_down(sl, off);
        sr += __shfl_down(sr, off);
    }
    if (lane == 0) {
        (br ? glB : glA)[b] = sl;
        (br ? grB : grA)[b] = sr;
    }
}

// col-mean of bf16 matrix; z selects problem. out pre-zeroed (by glgr2).
__global__ __launch_bounds__(256) void col_mean2(
    const unsigned short* __restrict__ g0, const unsigned short* __restrict__ g1,
    int C, float* __restrict__ o0, float* __restrict__ o1)
{
    const unsigned short* g = blockIdx.z ? g1 : g0;
    float* o = blockIdx.z ? o1 : o0;
    int c = blockIdx.x * 256 + threadIdx.x;
    int r0 = blockIdx.y * 128;
    float s = 0.f;
    for (int r = r0; r < r0 + 128; ++r) s += bf2f(g[(size_t)r * C + c]);
    atomicAdd(&o[c], s * (1.0f / 2048.0f));
}

// ---------------------------------------------------------------------------
// Fused sparse GAT attention+aggregation, both branches (grid = 2*NN).
// ---------------------------------------------------------------------------
template<int H, int F, typename OUT_T>
__global__ __launch_bounds__(256) void attn_agg2(
    const unsigned short* __restrict__ gb0, const unsigned short* __restrict__ gb1,
    int g_stride,
    const float* __restrict__ gl0, const float* __restrict__ gr0,
    const float* __restrict__ gl1, const float* __restrict__ gr1,
    const unsigned short* __restrict__ idx0, int is0, const int* __restrict__ cnt0,
    const unsigned short* __restrict__ idx1, int is1, const int* __restrict__ cnt1,
    const float* __restrict__ gmean0, const float* __restrict__ gmean1,
    OUT_T* __restrict__ dst0, OUT_T* __restrict__ dst1,
    int dst_stride, int co0, int co1,
    const float* __restrict__ resid, int mode)
{
    constexpr int HF = H * F;
    const int bid = blockIdx.x;
    const int br = bid >= NN;
    const int i = br ? bid - NN : bid;
    const unsigned short* gbp = br ? gb1 : gb0;
    const float* gl = br ? gl1 : gl0;
    const float* gr = br ? gr1 : gr0;
    const unsigned short* idx = br ? idx1 : idx0;
    const int is = br ? is1 : is0;
    const int* cnt = br ? cnt1 : cnt0;
    const float* gmean = br ? gmean1 : gmean0;
    OUT_T* dst = br ? dst1 : dst0;
    const int co = br ? co1 : co0;

    const int tid = threadIdx.x;
    const int lane = tid & 63, w = tid >> 6;
    const int n = cnt[i];

    if (n == 0) {
        for (int c = tid; c < HF; c += 256) {
            float v = gmean[c];
            if (mode == 0) v = (v > 0.f) ? v : expm1f(v);
            else           v += resid[(size_t)i * HF + c];
            store_out(&dst[(size_t)i * dst_stride + co + c], v);
        }
        return;
    }

    __shared__ float s_wred[4 * H];
    __shared__ float s_max[H], s_inv[H], s_glh[H];
    __shared__ float s_w[128 * H];
    __shared__ unsigned short s_j[128];

    if (tid < H) s_glh[tid] = gl[(size_t)i * H + tid];
    __syncthreads();
    float glh[H];
    #pragma unroll
    for (int h = 0; h < H; ++h) glh[h] = s_glh[h];

    const unsigned short* row_idx = idx + (size_t)i * is;

    // Pass 1: per-head max
    float pmax[H];
    #pragma unroll
    for (int h = 0; h < H; ++h) pmax[h] = -1e30f;
    for (int jj = tid; jj < n; jj += 256) {
        int j = row_idx[jj];
        if (H == 8) {
            float4 ga = *(const float4*)&gr[(size_t)j * 8];
            float4 gbv = *(const float4*)&gr[(size_t)j * 8 + 4];
            float sc[8] = {ga.x, ga.y, ga.z, ga.w, gbv.x, gbv.y, gbv.z, gbv.w};
            #pragma unroll
            for (int h = 0; h < H; ++h) {
                float s = glh[h] + sc[h];
                s = (s >= 0.f) ? s : 0.2f * s;
                pmax[h] = fmaxf(pmax[h], s);
            }
        } else {
            float s = glh[0] + gr[j];
            s = (s >= 0.f) ? s : 0.2f * s;
            pmax[0] = fmaxf(pmax[0], s);
        }
    }
    #pragma unroll
    for (int h = 0; h < H; ++h)
        #pragma unroll
        for (int off = 32; off > 0; off >>= 1)
            pmax[h] = fmaxf(pmax[h], __shfl_xor(pmax[h], off));
    if (lane == 0)
        #pragma unroll
        for (int h = 0; h < H; ++h) s_wred[w * H + h] = pmax[h];
    __syncthreads();
    if (tid < H)
        s_max[tid] = fmaxf(fmaxf(s_wred[tid], s_wred[H + tid]),
                           fmaxf(s_wred[2 * H + tid], s_wred[3 * H + tid]));
    __syncthreads();
    float mx[H];
    #pragma unroll
    for (int h = 0; h < H; ++h) mx[h] = s_max[h];

    // Pass 2: per-head exp-sum
    float psum[H];
    #pragma unroll
    for (int h = 0; h < H; ++h) psum[h] = 0.f;
    for (int jj = tid; jj < n; jj += 256) {
        int j = row_idx[jj];
        if (H == 8) {
            float4 ga = *(const float4*)&gr[(size_t)j * 8];
            float4 gbv = *(const float4*)&gr[(size_t)j * 8 + 4];
            float sc[8] = {ga.x, ga.y, ga.z, ga.w, gbv.x, gbv.y, gbv.z, gbv.w};
            #pragma unroll
            for (int h = 0; h < H; ++h) {
                float s = glh[h] + sc[h];
                s = (s >= 0.f) ? s : 0.2f * s;
                psum[h] += expf(s - mx[h]);
            }
        } else {
            float s = glh[0] + gr[j];
            s = (s >= 0.f) ? s : 0.2f * s;
            psum[0] += expf(s - mx[0]);
        }
    }
    #pragma unroll
    for (int h = 0; h < H; ++h)
        #pragma unroll
        for (int off = 32; off > 0; off >>= 1)
            psum[h] += __shfl_xor(psum[h], off);
    if (lane == 0)
        #pragma unroll
        for (int h = 0; h < H; ++h) s_wred[w * H + h] = psum[h];
    __syncthreads();
    if (tid < H)
        s_inv[tid] = 1.f / (s_wred[tid] + s_wred[H + tid] +
                            s_wred[2 * H + tid] + s_wred[3 * H + tid]);
    // ordering barrier supplied by first pass-3 iteration

    // Pass 3: bf16 gather, 4 consecutive cols/thread, unrolled x8
    const int cb = tid * 4;
    const bool active = (cb < HF);
    const int hh = (H == 8) ? (cb >> 7) : 0;
    float a0 = 0.f, a1 = 0.f, a2 = 0.f, a3 = 0.f;

    for (int c0 = 0; c0 < n; c0 += 128) {
        int m = min(128, n - c0);
        __syncthreads();
        for (int e = tid; e < m * H; e += 256) {
            int jj = (H == 8) ? (e >> 3) : e;
            int h  = (H == 8) ? (e & 7) : 0;
            int j = row_idx[c0 + jj];
            float s = glh[h] + gr[(size_t)j * H + h];
            s = (s >= 0.f) ? s : 0.2f * s;
            s_w[jj * H + h] = expf(s - s_max[h]) * s_inv[h];
            if (h == 0) s_j[jj] = (unsigned short)j;
        }
        __syncthreads();
        if (active) {
            int jj = 0;
            for (; jj + 8 <= m; jj += 8) {
                ushort4 v[8]; float wv[8];
                #pragma unroll
                for (int u = 0; u < 8; ++u) {
                    v[u] = *(const ushort4*)&gbp[(size_t)s_j[jj + u] * g_stride + cb];
                    wv[u] = s_w[(jj + u) * H + hh];
                }
                #pragma unroll
                for (int u = 0; u < 8; ++u) {
                    a0 += wv[u] * bf2f(v[u].x);
                    a1 += wv[u] * bf2f(v[u].y);
                    a2 += wv[u] * bf2f(v[u].z);
                    a3 += wv[u] * bf2f(v[u].w);
                }
            }
            for (; jj < m; ++jj) {
                ushort4 v0 = *(const ushort4*)&gbp[(size_t)s_j[jj] * g_stride + cb];
                float w0 = s_w[jj * H + hh];
                a0 += w0 * bf2f(v0.x); a1 += w0 * bf2f(v0.y);
                a2 += w0 * bf2f(v0.z); a3 += w0 * bf2f(v0.w);
            }
        }
    }

    if (active) {
        float vv[4] = {a0, a1, a2, a3};
        #pragma unroll
        for (int q = 0; q < 4; ++q) {
            float v = vv[q];
            if (mode == 0) v = (v > 0.f) ? v : expm1f(v);
            else           v += resid[(size_t)i * HF + cb + q];
            store_out(&dst[(size_t)i * dst_stride + co + cb + q], v);
        }
    }
}

// ---------------------------------------------------------------------------
extern "C" void kernel_launch(void* const* d_in, const int* in_sizes, int n_in,
                              void* d_out, int out_size, void* d_ws, size_t ws_size,
                              hipStream_t stream)
{
    const float* feature = (const float*)d_in[0];
    const float* adj     = (const float*)d_in[1];
    const float* g1W1 = (const float*)d_in[2];
    const float* g1a1 = (const float*)d_in[3];
    const float* g1W2 = (const float*)d_in[4];
    const float* g1a2 = (const float*)d_in[5];
    const float* g2W1 = (const float*)d_in[6];
    const float* g2a1 = (const float*)d_in[7];
    const float* g2W2 = (const float*)d_in[8];
    const float* g2a2 = (const float*)d_in[9];
    const float* Wf  = (const float*)d_in[10];
    const float* bfv = (const float*)d_in[11];
    const float* fW1 = (const float*)d_in[12];
    const float* fb1 = (const float*)d_in[13];
    const float* fW2 = (const float*)d_in[14];
    const float* fb2 = (const float*)d_in[15];
    const float* fW3 = (const float*)d_in[16];
    const float* fb3 = (const float*)d_in[17];
    const float* oW1 = (const float*)d_in[18];
    const float* ob1 = (const float*)d_in[19];
    const float* oW2 = (const float*)d_in[20];
    const float* ob2 = (const float*)d_in[21];
    float* out = (float*)d_out;

    char* ws = (char*)d_ws;
    size_t off = 0;
    auto alloc = [&](size_t bytes) -> void* {
        void* p = ws + off;
        off = (off + bytes + 255) & ~(size_t)255;
        return p;
    };
    typedef unsigned short bf_t;
    int* sen_cnt = (int*)alloc((size_t)NN * 4);
    int* sec_cnt = (int*)alloc((size_t)NN * 4);
    unsigned short* sen_idx = (unsigned short*)alloc((size_t)NN * MAXDEG * 2);
    unsigned short* sec_idx = (unsigned short*)alloc((size_t)NN * 8 * 2);
    bf_t*  g1b   = (bf_t*)alloc((size_t)NN * 2048 * 2);
    float* gl1a  = (float*)alloc((size_t)NN * NHEADS * 4);
    float* gr1a  = (float*)alloc((size_t)NN * NHEADS * 4);
    float* gl1b  = (float*)alloc((size_t)NN * NHEADS * 4);
    float* gr1b  = (float*)alloc((size_t)NN * NHEADS * 4);
    bf_t*  x1a   = (bf_t*)alloc((size_t)NN * DHID * 2);
    bf_t*  x1b   = (bf_t*)alloc((size_t)NN * DHID * 2);
    bf_t*  g2aB  = (bf_t*)alloc((size_t)NN * DIN * 2);
    bf_t*  g2bB  = (bf_t*)alloc((size_t)NN * DIN * 2);
    float* gl2a  = (float*)alloc((size_t)NN * 4);
    float* gr2a  = (float*)alloc((size_t)NN * 4);
    float* gl2b  = (float*)alloc((size_t)NN * 4);
    float* gr2b  = (float*)alloc((size_t)NN * 4);
    float* gmeanL1 = (float*)alloc((size_t)2048 * 4);
    float* gmeanL2 = (float*)alloc((size_t)1536 * 4);
    bf_t*  fcat  = (bf_t*)alloc((size_t)NN * (2 * DIN) * 2);
    bf_t*  fbuf  = (bf_t*)alloc((size_t)NN * DIN * 2);
    bf_t*  tA    = (bf_t*)alloc((size_t)NN * DFFN * 2);
    bf_t*  tB    = (bf_t*)alloc((size_t)NN * DFFN * 2);
    bf_t*  featb = (bf_t*)alloc((size_t)NN * DIN * 2);
    bf_t* W1T_AB = (bf_t*)alloc((size_t)2048 * DIN * 2);
    bf_t* g1W2T = (bf_t*)alloc((size_t)DHID * DIN * 2);
    bf_t* g2W2T = (bf_t*)alloc((size_t)DHID * DIN * 2);
    bf_t* WfT   = (bf_t*)alloc((size_t)(2 * DIN) * DIN * 2);
    bf_t* fW1T  = (bf_t*)alloc((size_t)DIN * DFFN * 2);
    bf_t* fW2T  = (bf_t*)alloc((size_t)DFFN * DFFN * 2);
    bf_t* fW3T  = (bf_t*)alloc((size_t)DFFN * DIN * 2);
    bf_t* oW1T  = (bf_t*)alloc((size_t)DIN * DFFN * 2);
    bf_t* oW2T  = (bf_t*)alloc((size_t)DFFN * DIN * 2);

    build_nbrs<<<NN, 256, 0, stream>>>(adj, sen_idx, sen_cnt, sec_idx, sec_cnt);

    TPJobs jobs;
    int cur = 0, nj = 0;
    auto addjob = [&](const float* s, bf_t* d, int K, int N, int trans) {
        jobs.j[nj] = {s, d, K, N, cur, trans};
        cur += (K / 32) * (N / 32);
        ++nj;
    };
    addjob(g1W1, W1T_AB, DIN, DHID, 1);
    addjob(g2W1, W1T_AB + (size_t)1024 * DIN, DIN, DHID, 1);
    addjob(g1W2, g1W2T, DHID, DIN, 1);
    addjob(g2W2, g2W2T, DHID, DIN, 1);
    addjob(Wf, WfT, 2 * DIN, DIN, 1);
    addjob(fW1, fW1T, DIN, DFFN, 1);
    addjob(fW2, fW2T, DFFN, DFFN, 1);
    addjob(fW3, fW3T, DFFN, DIN, 1);
    addjob(oW1, oW1T, DIN, DFFN, 1);
    addjob(oW2, oW2T, DFFN, DIN, 1);
    addjob(feature, featb, NN, DIN, 0);
    mega_tp<<<cur, 256, 0, stream>>>(jobs, nj);

    // Layer-1 GEMM, both branches fused: [2048,768] @ [768,2048] -> g1b bf16
    gemm_mfma<64, 128, bf_t><<<dim3(2048 / 128, NN / 64, 1), 256, 0, stream>>>(
        featb, nullptr, W1T_AB, nullptr, nullptr, nullptr,
        g1b, nullptr, nullptr, nullptr, NN, 2048, DIN, 0);

    glgr2<<<2 * NN * NHEADS, 64, 0, stream>>>(
        g1b, g1b + 1024, 2048, FPRIME, 3, NN * NHEADS,
        g1a1, g2a1, gl1a, gr1a, gl1b, gr1b, gmeanL1, 32);
    col_mean2<<<dim3(2048 / 256, 16, 1), 256, 0, stream>>>(
        g1b, nullptr, 2048, gmeanL1, nullptr);
    attn_agg2<NHEADS, FPRIME, bf_t><<<2 * NN, 256, 0, stream>>>(
        g1b, g1b + 1024, 2048,
        gl1a, gr1a, gl1b, gr1b,
        sen_idx, MAXDEG, sen_cnt, sec_idx, 8, sec_cnt,
        gmeanL1, gmeanL1 + 1024,
        x1a, x1b, DHID, 0, 0, nullptr, 0);

    // Layer-2 dual GEMM: x1{a,b} @ W2{a,b}^T -> g2{a,b} bf16
    gemm_mfma<64, 64, bf_t><<<dim3(DIN / 64, NN / 64, 2), 256, 0, stream>>>(
        x1a, x1b, g1W2T, g2W2T, nullptr, nullptr,
        g2aB, g2bB, nullptr, nullptr, NN, DIN, DHID, 0);

    glgr2<<<2 * NN, 64, 0, stream>>>(
        g2aB, g2bB, DIN, DIN, 0, NN,
        g1a2, g2a2, gl2a, gr2a, gl2b, gr2b, gmeanL2, 24);
    col_mean2<<<dim3(DIN / 256, 16, 2), 256, 0, stream>>>(
        g2aB, g2bB, DIN, gmeanL2, gmeanL2 + DIN);
    attn_agg2<1, DIN, bf_t><<<2 * NN, 256, 0, stream>>>(
        g2aB, g2bB, DIN,
        gl2a, gr2a, gl2b, gr2b,
        sen_idx, MAXDEG, sen_cnt, sec_idx, 8, sec_cnt,
        gmeanL2, gmeanL2 + DIN,
        fcat, fcat, 2 * DIN, DIN, 0, feature, 1);

    // Fusion + MLP chain
    gemm_mfma<64, 64, bf_t><<<dim3(DIN / 64, NN / 64, 1), 256, 0, stream>>>(
        fcat, nullptr, WfT, nullptr, bfv, nullptr,
        fbuf, nullptr, nullptr, nullptr, NN, DIN, 2 * DIN, 1);
    gemm_mfma<64, 128, bf_t><<<dim3(DFFN / 128, NN / 64, 1), 256, 0, stream>>>(
        fbuf, nullptr, fW1T, nullptr, fb1, nullptr,
        tA, nullptr, nullptr, nullptr, NN, DFFN, DIN, 1);
    gemm_mfma<64, 128, bf_t><<<dim3(DFFN / 128, NN / 64, 1), 256, 0, stream>>>(
        tA, nullptr, fW2T, nullptr, fb2, nullptr,
        tB, nullptr, nullptr, nullptr, NN, DFFN, DFFN, 1);
    gemm_mfma<64, 64, bf_t><<<dim3(DIN / 64, NN / 64, 1), 256, 0, stream>>>(
        tB, nullptr, fW3T, nullptr, fb3, nullptr,
        fbuf, nullptr, nullptr, nullptr, NN, DIN, DFFN, 1);
    gemm_mfma<64, 128, bf_t><<<dim3(DFFN / 128, NN / 64, 1), 256, 0, stream>>>(
        fbuf, nullptr, oW1T, nullptr, ob1, nullptr,
        tA, nullptr, nullptr, nullptr, NN, DFFN, DIN, 1);
    gemm_mfma<64, 64, float><<<dim3(DIN / 64, NN / 64, 1), 256, 0, stream>>>(
        tA, nullptr, oW2T, nullptr, ob2, feature,
        out, nullptr, nullptr, nullptr, NN, DIN, DFFN, 1);
}